// Round 1
// baseline (539.806 us; speedup 1.0000x reference)
//
#include <hip/hip_runtime.h>
#include <math.h>

#define E_DIM 512
#define H_DIM 8
#define D_DIM 64
#define WIN 128
#define L_SEQ 4096
#define B_SZ 2

// C[n,f] = sum_k A[n,k] * W[f,k] + bias[f]
// grid: (N/64, F/64), block 256 (tx = tid&15 -> cols, ty = tid>>4 -> rows)
__global__ __launch_bounds__(256) void gemm_xwT(const float* __restrict__ A,
                                                const float* __restrict__ W,
                                                const float* __restrict__ bias,
                                                float* __restrict__ C,
                                                int N, int F, int K) {
    __shared__ float As[64][17];  // [row][kk] padded
    __shared__ float Bs[16][65];  // [kk][col] padded
    const int tid = threadIdx.x;
    const int tx = tid & 15, ty = tid >> 4;
    const int n0 = blockIdx.x * 64;
    const int f0 = blockIdx.y * 64;
    const int lk = tid & 15;   // k-lane for loads
    const int lr = tid >> 4;   // row/col base for loads

    float acc[4][4] = {};

    for (int k0 = 0; k0 < K; k0 += 16) {
        // A tile: 64 rows x 16 k, coalesced along k
        #pragma unroll
        for (int i = 0; i < 4; i++)
            As[lr + 16 * i][lk] = A[(size_t)(n0 + lr + 16 * i) * K + k0 + lk];
        // W tile: store transposed into Bs[kk][col]
        #pragma unroll
        for (int j = 0; j < 4; j++)
            Bs[lk][lr + 16 * j] = W[(size_t)(f0 + lr + 16 * j) * K + k0 + lk];
        __syncthreads();

        #pragma unroll
        for (int k = 0; k < 16; k++) {
            float a[4], b[4];
            #pragma unroll
            for (int i = 0; i < 4; i++) a[i] = As[ty + 16 * i][k];
            #pragma unroll
            for (int j = 0; j < 4; j++) b[j] = Bs[k][tx + 16 * j];
            #pragma unroll
            for (int i = 0; i < 4; i++)
                #pragma unroll
                for (int j = 0; j < 4; j++)
                    acc[i][j] = fmaf(a[i], b[j], acc[i][j]);
        }
        __syncthreads();
    }

    #pragma unroll
    for (int i = 0; i < 4; i++) {
        const int n = n0 + ty + 16 * i;
        #pragma unroll
        for (int j = 0; j < 4; j++) {
            const int f = f0 + tx + 16 * j;
            C[(size_t)n * F + f] = acc[i][j] + bias[f];
        }
    }
}

// Windowed attention, one block per (64-query tile, h, b).
// qkv layout: [B, L, 3E] with q at +0, k at +E, v at +2E; head h at +h*64.
// attn_out layout: [B, L, E] (already the transpose-merged layout).
__global__ __launch_bounds__(256) void attn_win(const float* __restrict__ qkv,
                                                float* __restrict__ attn_out) {
    const int qs = blockIdx.x * 64;
    const int h  = blockIdx.y;
    const int b  = blockIdx.z;

    __shared__ float Qs[64][65];
    __shared__ float Ks[64][65];
    __shared__ float Vs[64][65];
    __shared__ float Sb[64][65];
    __shared__ float m_s[64], l_s[64], alpha_s[64];

    const int tid = threadIdx.x;
    const int tx = tid & 15, ty = tid >> 4;
    const float* base = qkv + (size_t)b * L_SEQ * (3 * E_DIM) + h * D_DIM;

    // load Q tile (coalesced: 64 lanes over d)
    {
        const int d = tid & 63, r0 = tid >> 6;
        for (int r = r0; r < 64; r += 4)
            Qs[r][d] = base[(size_t)(qs + r) * (3 * E_DIM) + d];
    }
    if (tid < 64) { m_s[tid] = -INFINITY; l_s[tid] = 0.f; }

    float o[4][4] = {};

    for (int kt = 0; kt < 5; kt++) {
        const int ks = qs - 128 + kt * 64;
        __syncthreads();  // prev iter done reading Ks/Vs/Sb
        {
            const int d = tid & 63, r0 = tid >> 6;
            for (int r = r0; r < 64; r += 4) {
                const int krow = ks + r;
                float kv = 0.f, vv = 0.f;
                if (krow >= 0 && krow < L_SEQ) {
                    kv = base[(size_t)krow * (3 * E_DIM) + E_DIM + d];
                    vv = base[(size_t)krow * (3 * E_DIM) + 2 * E_DIM + d];
                }
                Ks[r][d] = kv;
                Vs[r][d] = vv;
            }
        }
        __syncthreads();

        // S = Q K^T / 8 (4x4 per thread)
        float s[4][4] = {};
        for (int d = 0; d < 64; d++) {
            float a[4], bb[4];
            #pragma unroll
            for (int i = 0; i < 4; i++) a[i] = Qs[ty + 16 * i][d];
            #pragma unroll
            for (int j = 0; j < 4; j++) bb[j] = Ks[tx + 16 * j][d];
            #pragma unroll
            for (int i = 0; i < 4; i++)
                #pragma unroll
                for (int j = 0; j < 4; j++)
                    s[i][j] = fmaf(a[i], bb[j], s[i][j]);
        }
        #pragma unroll
        for (int i = 0; i < 4; i++) {
            const int q = qs + ty + 16 * i;
            #pragma unroll
            for (int j = 0; j < 4; j++) {
                const int k = ks + tx + 16 * j;
                const int dist = (q > k) ? (q - k) : (k - q);
                const bool ok = (k >= 0) && (k < L_SEQ) && (dist > 0) && (dist <= WIN);
                Sb[ty + 16 * i][tx + 16 * j] = ok ? s[i][j] * 0.125f : -INFINITY;
            }
        }
        __syncthreads();

        // online softmax stats, one thread per query row
        if (tid < 64) {
            const int q = tid;
            const float mold = m_s[q];
            float mk = -INFINITY;
            for (int k = 0; k < 64; k++) mk = fmaxf(mk, Sb[q][k]);
            const float mnew = fmaxf(mold, mk);
            float alpha, psum = 0.f;
            if (mnew == -INFINITY) {
                alpha = 1.f;
                for (int k = 0; k < 64; k++) Sb[q][k] = 0.f;
            } else {
                alpha = __expf(mold - mnew);  // exp(-inf)=0 handles first tile
                for (int k = 0; k < 64; k++) {
                    const float sv = Sb[q][k];
                    const float p = (sv == -INFINITY) ? 0.f : __expf(sv - mnew);
                    Sb[q][k] = p;
                    psum += p;
                }
            }
            m_s[q] = mnew;
            l_s[q] = l_s[q] * alpha + psum;
            alpha_s[q] = alpha;
        }
        __syncthreads();

        // O = O*alpha + P @ V  (4 q-rows x 4 d-cols per thread)
        float al[4];
        #pragma unroll
        for (int i = 0; i < 4; i++) al[i] = alpha_s[ty + 16 * i];
        #pragma unroll
        for (int i = 0; i < 4; i++)
            #pragma unroll
            for (int j = 0; j < 4; j++) o[i][j] *= al[i];
        for (int k = 0; k < 64; k++) {
            float p[4], v[4];
            #pragma unroll
            for (int i = 0; i < 4; i++) p[i] = Sb[ty + 16 * i][k];
            #pragma unroll
            for (int j = 0; j < 4; j++) v[j] = Vs[k][tx + 16 * j];
            #pragma unroll
            for (int i = 0; i < 4; i++)
                #pragma unroll
                for (int j = 0; j < 4; j++)
                    o[i][j] = fmaf(p[i], v[j], o[i][j]);
        }
    }

    // write attention output: [b, qs+q, h*64+d]
    float* outp = attn_out + ((size_t)b * L_SEQ + qs) * E_DIM + h * D_DIM;
    #pragma unroll
    for (int i = 0; i < 4; i++) {
        const int q = ty + 16 * i;
        const float inv_l = 1.f / l_s[q];
        #pragma unroll
        for (int j = 0; j < 4; j++)
            outp[(size_t)q * E_DIM + tx + 16 * j] = o[i][j] * inv_l;
    }
}

extern "C" void kernel_launch(void* const* d_in, const int* in_sizes, int n_in,
                              void* d_out, int out_size, void* d_ws, size_t ws_size,
                              hipStream_t stream) {
    const float* x         = (const float*)d_in[0];  // [B, L, E]
    const float* in_proj_w = (const float*)d_in[1];  // [3E, E]
    const float* in_proj_b = (const float*)d_in[2];  // [3E]
    const float* out_w     = (const float*)d_in[3];  // [E, E]
    const float* out_b     = (const float*)d_in[4];  // [E]
    float* out = (float*)d_out;                      // [B, L, E]

    const int N = B_SZ * L_SEQ;  // 8192 token rows
    float* ws = (float*)d_ws;
    float* qkv = ws;                                   // [B, L, 3E] = 12.58M floats
    float* attn = ws + (size_t)N * 3 * E_DIM;          // [B, L, E]  = 4.19M floats

    // 1) QKV projection: [8192, 512] x [1536, 512]^T
    dim3 g1(N / 64, (3 * E_DIM) / 64);
    gemm_xwT<<<g1, 256, 0, stream>>>(x, in_proj_w, in_proj_b, qkv, N, 3 * E_DIM, E_DIM);

    // 2) windowed attention
    dim3 g2(L_SEQ / 64, H_DIM, B_SZ);
    attn_win<<<g2, 256, 0, stream>>>(qkv, attn);

    // 3) output projection: [8192, 512] x [512, 512]^T
    dim3 g3(N / 64, E_DIM / 64);
    gemm_xwT<<<g3, 256, 0, stream>>>(attn, out_w, out_b, out, N, E_DIM, E_DIM);
}

// Round 2
// 315.038 us; speedup vs baseline: 1.7135x; 1.7135x over previous
//
#include <hip/hip_runtime.h>
#include <math.h>

#define E_DIM 512
#define H_DIM 8
#define D_DIM 64
#define WIN 128
#define L_SEQ 4096
#define B_SZ 2

typedef unsigned short ushort_t;
typedef unsigned int uint_t;
typedef __attribute__((ext_vector_type(8))) __bf16 bf16x8;
typedef __attribute__((ext_vector_type(4))) float f32x4;

// ---------- bf16 helpers (manual, RNE) ----------
__device__ __forceinline__ ushort_t f2bf(float f) {
    uint_t u = __float_as_uint(f);
    u = u + 0x7fffu + ((u >> 16) & 1u);
    return (ushort_t)(u >> 16);
}
__device__ __forceinline__ float bf2f(ushort_t h) {
    return __uint_as_float((uint_t)h << 16);
}

__device__ __forceinline__ void gload16(const ushort_t* g, ushort_t* l) {
    __builtin_amdgcn_global_load_lds(
        (const __attribute__((address_space(1))) void*)g,
        (__attribute__((address_space(3))) void*)l,
        16, 0, 0);
}

// ---------- split-convert: fp32 -> (hi, lo) bf16, 3 tensors fused ----------
// sizes in float4 groups: x 1048576, w1 196608, w2 65536  (total 1310720)
__global__ __launch_bounds__(256) void convert3(
    const float* __restrict__ x,  ushort_t* __restrict__ xh,  ushort_t* __restrict__ xl,
    const float* __restrict__ w1, ushort_t* __restrict__ w1h, ushort_t* __restrict__ w1l,
    const float* __restrict__ w2, ushort_t* __restrict__ w2h, ushort_t* __restrict__ w2l) {
    int gid = blockIdx.x * 256 + threadIdx.x;
    const float* src; ushort_t* dh; ushort_t* dl; int idx;
    if (gid < 1048576)      { src = x;  dh = xh;  dl = xl;  idx = gid; }
    else if (gid < 1245184) { src = w1; dh = w1h; dl = w1l; idx = gid - 1048576; }
    else                    { src = w2; dh = w2h; dl = w2l; idx = gid - 1245184; }
    float4 v = ((const float4*)src)[idx];
    ushort4 h, l;
    {
        ushort_t a;
        a = f2bf(v.x); h.x = a; l.x = f2bf(v.x - bf2f(a));
        a = f2bf(v.y); h.y = a; l.y = f2bf(v.y - bf2f(a));
        a = f2bf(v.z); h.z = a; l.z = f2bf(v.z - bf2f(a));
        a = f2bf(v.w); h.w = a; l.w = f2bf(v.w - bf2f(a));
    }
    ((ushort4*)dh)[idx] = h;
    ((ushort4*)dl)[idx] = l;
}

// ---------- split-bf16 MFMA GEMM: C = A * W^T + bias ----------
// A: [M,K] as hi/lo bf16, W: [N,K] as hi/lo bf16, C: [M,N] fp32.
// Tile 128x128, BK=32. 256 threads = 4 waves in 2x2; wave does 64x64 via
// 4x4 tiles of 16x16x32 MFMA; 3 MFMA terms per tile (hh, hl, lh).
__global__ __launch_bounds__(256) void gemm_mfma_split(
    const ushort_t* __restrict__ Ah, const ushort_t* __restrict__ Al,
    const ushort_t* __restrict__ Wh, const ushort_t* __restrict__ Wl,
    const float* __restrict__ bias, float* __restrict__ C,
    int M, int N, int K) {
    __shared__ __align__(16) ushort_t sAh[128 * 32];
    __shared__ __align__(16) ushort_t sAl[128 * 32];
    __shared__ __align__(16) ushort_t sWh[128 * 32];
    __shared__ __align__(16) ushort_t sWl[128 * 32];

    const int tid  = threadIdx.x;
    const int lane = tid & 63;
    const int w    = tid >> 6;
    const int wm   = w & 1, wn = w >> 1;
    const int ln   = lane & 15;
    const int quad = lane >> 4;

    // staging: wave w covers rows [32w, 32w+32); lane covers 16B of one row
    const int srow = 32 * w + (lane >> 2);
    const int skof = (lane & 3) * 8;
    const size_t aoff  = (size_t)(blockIdx.x * 128 + srow) * K + skof;
    const size_t woff  = (size_t)(blockIdx.y * 128 + srow) * K + skof;
    const size_t row16 = (size_t)16 * K;
    const ushort_t* gAh = Ah + aoff;
    const ushort_t* gAl = Al + aoff;
    const ushort_t* gWh = Wh + woff;
    const ushort_t* gWl = Wl + woff;
    const int lbase = (32 * w) * 32;  // LDS element offset, wave-uniform

    f32x4 acc[4][4];
    const f32x4 zero = {0.f, 0.f, 0.f, 0.f};
    #pragma unroll
    for (int i = 0; i < 4; i++)
        #pragma unroll
        for (int j = 0; j < 4; j++) acc[i][j] = zero;

    for (int k0 = 0; k0 < K; k0 += 32) {
        __syncthreads();
        gload16(gAh + k0,         &sAh[lbase]);
        gload16(gAh + k0 + row16, &sAh[lbase + 512]);
        gload16(gAl + k0,         &sAl[lbase]);
        gload16(gAl + k0 + row16, &sAl[lbase + 512]);
        gload16(gWh + k0,         &sWh[lbase]);
        gload16(gWh + k0 + row16, &sWh[lbase + 512]);
        gload16(gWl + k0,         &sWl[lbase]);
        gload16(gWl + k0 + row16, &sWl[lbase + 512]);
        __syncthreads();

        bf16x8 fah[4], fal[4], fbh[4], fbl[4];
        #pragma unroll
        for (int t = 0; t < 4; t++) {
            const int ra = (wm * 64 + t * 16 + ln) * 32 + quad * 8;
            const int rb = (wn * 64 + t * 16 + ln) * 32 + quad * 8;
            fah[t] = *(const bf16x8*)&sAh[ra];
            fal[t] = *(const bf16x8*)&sAl[ra];
            fbh[t] = *(const bf16x8*)&sWh[rb];
            fbl[t] = *(const bf16x8*)&sWl[rb];
        }
        #pragma unroll
        for (int i = 0; i < 4; i++)
            #pragma unroll
            for (int j = 0; j < 4; j++) {
                acc[i][j] = __builtin_amdgcn_mfma_f32_16x16x32_bf16(fah[i], fbh[j], acc[i][j], 0, 0, 0);
                acc[i][j] = __builtin_amdgcn_mfma_f32_16x16x32_bf16(fah[i], fbl[j], acc[i][j], 0, 0, 0);
                acc[i][j] = __builtin_amdgcn_mfma_f32_16x16x32_bf16(fal[i], fbh[j], acc[i][j], 0, 0, 0);
            }
    }

    // epilogue: C/D layout col=lane&15, row=quad*4+r
    const int row0 = blockIdx.x * 128 + wm * 64 + quad * 4;
    const int col0 = blockIdx.y * 128 + wn * 64 + ln;
    float bv[4];
    #pragma unroll
    for (int j = 0; j < 4; j++) bv[j] = bias[col0 + j * 16];
    #pragma unroll
    for (int i = 0; i < 4; i++)
        #pragma unroll
        for (int j = 0; j < 4; j++)
            #pragma unroll
            for (int r = 0; r < 4; r++)
                C[(size_t)(row0 + i * 16 + r) * N + col0 + j * 16] = acc[i][j][r] + bv[j];
}

// ---------- windowed attention (fp32 core), writes split-bf16 output ----------
__global__ __launch_bounds__(256) void attn_win(const float* __restrict__ qkv,
                                                ushort_t* __restrict__ attn_hi,
                                                ushort_t* __restrict__ attn_lo) {
    const int qs = blockIdx.x * 64;
    const int h  = blockIdx.y;
    const int b  = blockIdx.z;

    __shared__ float Qs[64][65];
    __shared__ float Ks[64][65];
    __shared__ float Vs[64][65];
    __shared__ float Sb[64][65];
    __shared__ float m_s[64], l_s[64], alpha_s[64];

    const int tid = threadIdx.x;
    const int tx = tid & 15, ty = tid >> 4;
    const float* base = qkv + (size_t)b * L_SEQ * (3 * E_DIM) + h * D_DIM;

    {
        const int d = tid & 63, r0 = tid >> 6;
        for (int r = r0; r < 64; r += 4)
            Qs[r][d] = base[(size_t)(qs + r) * (3 * E_DIM) + d];
    }
    if (tid < 64) { m_s[tid] = -INFINITY; l_s[tid] = 0.f; }

    float o[4][4] = {};

    for (int kt = 0; kt < 5; kt++) {
        const int ks = qs - 128 + kt * 64;
        __syncthreads();
        {
            const int d = tid & 63, r0 = tid >> 6;
            for (int r = r0; r < 64; r += 4) {
                const int krow = ks + r;
                float kv = 0.f, vv = 0.f;
                if (krow >= 0 && krow < L_SEQ) {
                    kv = base[(size_t)krow * (3 * E_DIM) + E_DIM + d];
                    vv = base[(size_t)krow * (3 * E_DIM) + 2 * E_DIM + d];
                }
                Ks[r][d] = kv;
                Vs[r][d] = vv;
            }
        }
        __syncthreads();

        float s[4][4] = {};
        for (int d = 0; d < 64; d++) {
            float a[4], bb[4];
            #pragma unroll
            for (int i = 0; i < 4; i++) a[i] = Qs[ty + 16 * i][d];
            #pragma unroll
            for (int j = 0; j < 4; j++) bb[j] = Ks[tx + 16 * j][d];
            #pragma unroll
            for (int i = 0; i < 4; i++)
                #pragma unroll
                for (int j = 0; j < 4; j++)
                    s[i][j] = fmaf(a[i], bb[j], s[i][j]);
        }
        #pragma unroll
        for (int i = 0; i < 4; i++) {
            const int q = qs + ty + 16 * i;
            #pragma unroll
            for (int j = 0; j < 4; j++) {
                const int k = ks + tx + 16 * j;
                const int dist = (q > k) ? (q - k) : (k - q);
                const bool ok = (k >= 0) && (k < L_SEQ) && (dist > 0) && (dist <= WIN);
                Sb[ty + 16 * i][tx + 16 * j] = ok ? s[i][j] * 0.125f : -INFINITY;
            }
        }
        __syncthreads();

        if (tid < 64) {
            const int q = tid;
            const float mold = m_s[q];
            float mk = -INFINITY;
            for (int k = 0; k < 64; k++) mk = fmaxf(mk, Sb[q][k]);
            const float mnew = fmaxf(mold, mk);
            float alpha, psum = 0.f;
            if (mnew == -INFINITY) {
                alpha = 1.f;
                for (int k = 0; k < 64; k++) Sb[q][k] = 0.f;
            } else {
                alpha = __expf(mold - mnew);
                for (int k = 0; k < 64; k++) {
                    const float sv = Sb[q][k];
                    const float p = (sv == -INFINITY) ? 0.f : __expf(sv - mnew);
                    Sb[q][k] = p;
                    psum += p;
                }
            }
            m_s[q] = mnew;
            l_s[q] = l_s[q] * alpha + psum;
            alpha_s[q] = alpha;
        }
        __syncthreads();

        float al[4];
        #pragma unroll
        for (int i = 0; i < 4; i++) al[i] = alpha_s[ty + 16 * i];
        #pragma unroll
        for (int i = 0; i < 4; i++)
            #pragma unroll
            for (int j = 0; j < 4; j++) o[i][j] *= al[i];
        for (int k = 0; k < 64; k++) {
            float p[4], v[4];
            #pragma unroll
            for (int i = 0; i < 4; i++) p[i] = Sb[ty + 16 * i][k];
            #pragma unroll
            for (int j = 0; j < 4; j++) v[j] = Vs[k][tx + 16 * j];
            #pragma unroll
            for (int i = 0; i < 4; i++)
                #pragma unroll
                for (int j = 0; j < 4; j++)
                    o[i][j] = fmaf(p[i], v[j], o[i][j]);
        }
    }

    ushort_t* oh = attn_hi + ((size_t)b * L_SEQ + qs) * E_DIM + h * D_DIM;
    ushort_t* ol = attn_lo + ((size_t)b * L_SEQ + qs) * E_DIM + h * D_DIM;
    #pragma unroll
    for (int i = 0; i < 4; i++) {
        const int q = ty + 16 * i;
        const float inv_l = 1.f / l_s[q];
        #pragma unroll
        for (int j = 0; j < 4; j++) {
            const float v = o[i][j] * inv_l;
            const ushort_t hh = f2bf(v);
            oh[(size_t)q * E_DIM + tx + 16 * j] = hh;
            ol[(size_t)q * E_DIM + tx + 16 * j] = f2bf(v - bf2f(hh));
        }
    }
}

extern "C" void kernel_launch(void* const* d_in, const int* in_sizes, int n_in,
                              void* d_out, int out_size, void* d_ws, size_t ws_size,
                              hipStream_t stream) {
    const float* x         = (const float*)d_in[0];  // [B, L, E]
    const float* in_proj_w = (const float*)d_in[1];  // [3E, E]
    const float* in_proj_b = (const float*)d_in[2];  // [3E]
    const float* out_w     = (const float*)d_in[3];  // [E, E]
    const float* out_b     = (const float*)d_in[4];  // [E]
    float* out = (float*)d_out;                      // [B, L, E]

    const int N = B_SZ * L_SEQ;  // 8192 token rows

    char* p = (char*)d_ws;
    float* qkv = (float*)p;        p += (size_t)N * 3 * E_DIM * 4;  // 50.3 MB
    ushort_t* xh  = (ushort_t*)p;  p += (size_t)N * E_DIM * 2;
    ushort_t* xl  = (ushort_t*)p;  p += (size_t)N * E_DIM * 2;
    ushort_t* w1h = (ushort_t*)p;  p += (size_t)3 * E_DIM * E_DIM * 2;
    ushort_t* w1l = (ushort_t*)p;  p += (size_t)3 * E_DIM * E_DIM * 2;
    ushort_t* w2h = (ushort_t*)p;  p += (size_t)E_DIM * E_DIM * 2;
    ushort_t* w2l = (ushort_t*)p;  p += (size_t)E_DIM * E_DIM * 2;
    ushort_t* ath = (ushort_t*)p;  p += (size_t)N * E_DIM * 2;
    ushort_t* atl = (ushort_t*)p;  p += (size_t)N * E_DIM * 2;
    // total ~88.1 MB

    // 1) split-convert x, in_proj_w, out_w
    convert3<<<5120, 256, 0, stream>>>(x, xh, xl, in_proj_w, w1h, w1l, out_w, w2h, w2l);

    // 2) QKV projection: [8192,512] x [1536,512]^T -> fp32 qkv
    gemm_mfma_split<<<dim3(64, 12), 256, 0, stream>>>(xh, xl, w1h, w1l, in_proj_b, qkv,
                                                      N, 3 * E_DIM, E_DIM);

    // 3) windowed attention (fp32), emits split-bf16 output
    attn_win<<<dim3(L_SEQ / 64, H_DIM, B_SZ), 256, 0, stream>>>(qkv, ath, atl);

    // 4) output projection: [8192,512] x [512,512]^T -> fp32 out
    gemm_mfma_split<<<dim3(64, 4), 256, 0, stream>>>(ath, atl, w2h, w2l, out_b, out,
                                                     N, E_DIM, E_DIM);
}

// Round 3
// 215.940 us; speedup vs baseline: 2.4998x; 1.4589x over previous
//
#include <hip/hip_runtime.h>
#include <math.h>

#define E_DIM 512
#define H_DIM 8
#define WIN 128
#define L_SEQ 4096
#define B_SZ 2
#define QKV_PITCH (3 * E_DIM)

typedef unsigned short ushort_t;
typedef unsigned int uint_t;
typedef __attribute__((ext_vector_type(8))) __bf16 bf16x8;
typedef __attribute__((ext_vector_type(4))) float f32x4;

// ---------- bf16 helpers (manual, RNE) ----------
__device__ __forceinline__ ushort_t f2bf(float f) {
    uint_t u = __float_as_uint(f);
    u = u + 0x7fffu + ((u >> 16) & 1u);
    return (ushort_t)(u >> 16);
}
__device__ __forceinline__ float bf2f(ushort_t h) {
    return __uint_as_float((uint_t)h << 16);
}

__device__ __forceinline__ void gload16(const ushort_t* g, ushort_t* l) {
    __builtin_amdgcn_global_load_lds(
        (const __attribute__((address_space(1))) void*)g,
        (__attribute__((address_space(3))) void*)l,
        16, 0, 0);
}

// ---------- split-convert: fp32 -> (hi, lo) bf16, 3 tensors fused ----------
__global__ __launch_bounds__(256) void convert3(
    const float* __restrict__ x,  ushort_t* __restrict__ xh,  ushort_t* __restrict__ xl,
    const float* __restrict__ w1, ushort_t* __restrict__ w1h, ushort_t* __restrict__ w1l,
    const float* __restrict__ w2, ushort_t* __restrict__ w2h, ushort_t* __restrict__ w2l) {
    int gid = blockIdx.x * 256 + threadIdx.x;
    const float* src; ushort_t* dh; ushort_t* dl; int idx;
    if (gid < 1048576)      { src = x;  dh = xh;  dl = xl;  idx = gid; }
    else if (gid < 1245184) { src = w1; dh = w1h; dl = w1l; idx = gid - 1048576; }
    else                    { src = w2; dh = w2h; dl = w2l; idx = gid - 1245184; }
    float4 v = ((const float4*)src)[idx];
    ushort4 h, l;
    {
        ushort_t a;
        a = f2bf(v.x); h.x = a; l.x = f2bf(v.x - bf2f(a));
        a = f2bf(v.y); h.y = a; l.y = f2bf(v.y - bf2f(a));
        a = f2bf(v.z); h.z = a; l.z = f2bf(v.z - bf2f(a));
        a = f2bf(v.w); h.w = a; l.w = f2bf(v.w - bf2f(a));
    }
    ((ushort4*)dh)[idx] = h;
    ((ushort4*)dl)[idx] = l;
}

// ---------- split-bf16 MFMA GEMM: C = A * W^T + bias ----------
template <bool BF16_OUT>
__global__ __launch_bounds__(256) void gemm_mfma_split(
    const ushort_t* __restrict__ Ah, const ushort_t* __restrict__ Al,
    const ushort_t* __restrict__ Wh, const ushort_t* __restrict__ Wl,
    const float* __restrict__ bias, float* __restrict__ C,
    ushort_t* __restrict__ Ch, ushort_t* __restrict__ Cl,
    int M, int N, int K) {
    __shared__ __align__(16) ushort_t sAh[128 * 32];
    __shared__ __align__(16) ushort_t sAl[128 * 32];
    __shared__ __align__(16) ushort_t sWh[128 * 32];
    __shared__ __align__(16) ushort_t sWl[128 * 32];

    const int tid  = threadIdx.x;
    const int lane = tid & 63;
    const int w    = tid >> 6;
    const int wm   = w & 1, wn = w >> 1;
    const int ln   = lane & 15;
    const int quad = lane >> 4;

    const int srow = 32 * w + (lane >> 2);
    const int skof = (lane & 3) * 8;
    const size_t aoff  = (size_t)(blockIdx.x * 128 + srow) * K + skof;
    const size_t woff  = (size_t)(blockIdx.y * 128 + srow) * K + skof;
    const size_t row16 = (size_t)16 * K;
    const ushort_t* gAh = Ah + aoff;
    const ushort_t* gAl = Al + aoff;
    const ushort_t* gWh = Wh + woff;
    const ushort_t* gWl = Wl + woff;
    const int lbase = (32 * w) * 32;

    f32x4 acc[4][4];
    const f32x4 zero = {0.f, 0.f, 0.f, 0.f};
    #pragma unroll
    for (int i = 0; i < 4; i++)
        #pragma unroll
        for (int j = 0; j < 4; j++) acc[i][j] = zero;

    for (int k0 = 0; k0 < K; k0 += 32) {
        __syncthreads();
        gload16(gAh + k0,         &sAh[lbase]);
        gload16(gAh + k0 + row16, &sAh[lbase + 512]);
        gload16(gAl + k0,         &sAl[lbase]);
        gload16(gAl + k0 + row16, &sAl[lbase + 512]);
        gload16(gWh + k0,         &sWh[lbase]);
        gload16(gWh + k0 + row16, &sWh[lbase + 512]);
        gload16(gWl + k0,         &sWl[lbase]);
        gload16(gWl + k0 + row16, &sWl[lbase + 512]);
        __syncthreads();

        bf16x8 fah[4], fal[4], fbh[4], fbl[4];
        #pragma unroll
        for (int t = 0; t < 4; t++) {
            const int ra = (wm * 64 + t * 16 + ln) * 32 + quad * 8;
            const int rb = (wn * 64 + t * 16 + ln) * 32 + quad * 8;
            fah[t] = *(const bf16x8*)&sAh[ra];
            fal[t] = *(const bf16x8*)&sAl[ra];
            fbh[t] = *(const bf16x8*)&sWh[rb];
            fbl[t] = *(const bf16x8*)&sWl[rb];
        }
        #pragma unroll
        for (int i = 0; i < 4; i++)
            #pragma unroll
            for (int j = 0; j < 4; j++) {
                acc[i][j] = __builtin_amdgcn_mfma_f32_16x16x32_bf16(fah[i], fbh[j], acc[i][j], 0, 0, 0);
                acc[i][j] = __builtin_amdgcn_mfma_f32_16x16x32_bf16(fah[i], fbl[j], acc[i][j], 0, 0, 0);
                acc[i][j] = __builtin_amdgcn_mfma_f32_16x16x32_bf16(fal[i], fbh[j], acc[i][j], 0, 0, 0);
            }
    }

    const int row0 = blockIdx.x * 128 + wm * 64 + quad * 4;
    const int col0 = blockIdx.y * 128 + wn * 64 + ln;
    float bv[4];
    #pragma unroll
    for (int j = 0; j < 4; j++) bv[j] = bias[col0 + j * 16];
    #pragma unroll
    for (int i = 0; i < 4; i++)
        #pragma unroll
        for (int j = 0; j < 4; j++)
            #pragma unroll
            for (int r = 0; r < 4; r++) {
                const size_t idx = (size_t)(row0 + i * 16 + r) * N + col0 + j * 16;
                const float v = acc[i][j][r] + bv[j];
                if (BF16_OUT) {
                    const ushort_t hh = f2bf(v);
                    Ch[idx] = hh;
                    Cl[idx] = f2bf(v - bf2f(hh));
                } else {
                    C[idx] = v;
                }
            }
}

// ---------- MFMA windowed attention ----------
#define VP 80
__device__ __forceinline__ int swz(int row, int col) {
    return row * VP + ((col + 16 * ((row >> 2) & 3)) & 63);
}

__global__ __launch_bounds__(256) void attn_mfma(
    const ushort_t* __restrict__ qkvh, const ushort_t* __restrict__ qkvl,
    ushort_t* __restrict__ outh, ushort_t* __restrict__ outl) {
    __shared__ __align__(16) ushort_t sVh[64 * VP];
    __shared__ __align__(16) ushort_t sVl[64 * VP];
    __shared__ __align__(16) ushort_t sPh[64 * VP];
    __shared__ __align__(16) ushort_t sPl[64 * VP];

    const int qs = blockIdx.x * 64;
    const int h = blockIdx.y, b = blockIdx.z;
    const int tid = threadIdx.x, lane = tid & 63;
    const int w = tid >> 6, ln = lane & 15, quad = lane >> 4;

    const size_t bbase = (size_t)b * L_SEQ * QKV_PITCH;
    const int hoff = h * 64;

    // Q fragments (persistent in regs): A-layout [m=ln][k=quad*8+j], kk in {0,1}
    bf16x8 qf[2][2];
    {
        const size_t qoff = bbase + (size_t)(qs + 16 * w + ln) * QKV_PITCH + hoff + quad * 8;
        qf[0][0] = *(const bf16x8*)(qkvh + qoff);
        qf[1][0] = *(const bf16x8*)(qkvh + qoff + 32);
        qf[0][1] = *(const bf16x8*)(qkvl + qoff);
        qf[1][1] = *(const bf16x8*)(qkvl + qoff + 32);
    }

    f32x4 oacc[4];
    const f32x4 zero = {0.f, 0.f, 0.f, 0.f};
    #pragma unroll
    for (int dt = 0; dt < 4; dt++) oacc[dt] = zero;
    float m_run[4], l_run[4];
    #pragma unroll
    for (int r = 0; r < 4; r++) { m_run[r] = -1e30f; l_run[r] = 0.f; }

    const float cscale = 0.125f * 1.44269504f;  // 1/sqrt(D) * log2(e)

    for (int kt = 0; kt < 5; kt++) {
        const int ks = qs - 128 + kt * 64;

        // --- global loads for V staging (regs first) ---
        bf16x8 vh0, vh1, vl0, vl1;
        {
            int gk = ks + lane; gk = gk < 0 ? 0 : (gk >= L_SEQ ? L_SEQ - 1 : gk);
            const size_t voff = bbase + (size_t)gk * QKV_PITCH + 2 * E_DIM + hoff;
            vh0 = *(const bf16x8*)(qkvh + voff + w * 8);
            vh1 = *(const bf16x8*)(qkvh + voff + (w + 4) * 8);
            vl0 = *(const bf16x8*)(qkvl + voff + w * 8);
            vl1 = *(const bf16x8*)(qkvl + voff + (w + 4) * 8);
        }
        // --- K fragments (B-layout, direct from global) ---
        bf16x8 kf[4][2][2];
        #pragma unroll
        for (int jt = 0; jt < 4; jt++) {
            const bool dead = (kt == 0 && jt < w) || (kt == 4 && jt > w);
            if (!dead) {
                int gk = ks + 16 * jt + ln; gk = gk < 0 ? 0 : (gk >= L_SEQ - 1 ? L_SEQ - 1 : gk);
                const size_t koff = bbase + (size_t)gk * QKV_PITCH + E_DIM + hoff + quad * 8;
                kf[jt][0][0] = *(const bf16x8*)(qkvh + koff);
                kf[jt][1][0] = *(const bf16x8*)(qkvh + koff + 32);
                kf[jt][0][1] = *(const bf16x8*)(qkvl + koff);
                kf[jt][1][1] = *(const bf16x8*)(qkvl + koff + 32);
            }
        }

        __syncthreads();  // previous PV finished reading sV/sP

        // --- write V^T into LDS (swizzled) ---
        #pragma unroll
        for (int j = 0; j < 8; j++) {
            const int d0 = w * 8 + j, d1 = (w + 4) * 8 + j;
            sVh[swz(d0, lane)] = ((const ushort_t*)&vh0)[j];
            sVh[swz(d1, lane)] = ((const ushort_t*)&vh1)[j];
            sVl[swz(d0, lane)] = ((const ushort_t*)&vl0)[j];
            sVl[swz(d1, lane)] = ((const ushort_t*)&vl1)[j];
        }

        // --- S = Q K^T (split: hh + hl + lh) ---
        f32x4 sacc[4];
        #pragma unroll
        for (int jt = 0; jt < 4; jt++) {
            f32x4 a = zero;
            const bool dead = (kt == 0 && jt < w) || (kt == 4 && jt > w);
            if (!dead) {
                #pragma unroll
                for (int kk = 0; kk < 2; kk++) {
                    a = __builtin_amdgcn_mfma_f32_16x16x32_bf16(qf[kk][0], kf[jt][kk][0], a, 0, 0, 0);
                    a = __builtin_amdgcn_mfma_f32_16x16x32_bf16(qf[kk][0], kf[jt][kk][1], a, 0, 0, 0);
                    a = __builtin_amdgcn_mfma_f32_16x16x32_bf16(qf[kk][1], kf[jt][kk][0], a, 0, 0, 0);
                }
            }
            sacc[jt] = a;
        }

        // --- mask + online softmax (registers, all lanes) ---
        float u[4][4];
        #pragma unroll
        for (int jt = 0; jt < 4; jt++) {
            const int kcol = ks + 16 * jt + ln;
            #pragma unroll
            for (int r = 0; r < 4; r++) {
                const int qrow = qs + 16 * w + quad * 4 + r;
                const int dist = qrow > kcol ? qrow - kcol : kcol - qrow;
                const bool ok = (kcol >= 0) && (kcol < L_SEQ) && (dist >= 1) && (dist <= WIN);
                u[jt][r] = ok ? sacc[jt][r] * cscale : -INFINITY;
            }
        }
        float mk[4];
        #pragma unroll
        for (int r = 0; r < 4; r++)
            mk[r] = fmaxf(fmaxf(u[0][r], u[1][r]), fmaxf(u[2][r], u[3][r]));
        #pragma unroll
        for (int off = 1; off <= 8; off <<= 1)
            #pragma unroll
            for (int r = 0; r < 4; r++)
                mk[r] = fmaxf(mk[r], __shfl_xor(mk[r], off));

        float alpha[4], psum[4], p[4][4];
        #pragma unroll
        for (int r = 0; r < 4; r++) {
            const float mnew = fmaxf(fmaxf(m_run[r], mk[r]), -1e30f);
            alpha[r] = exp2f(m_run[r] - mnew);
            m_run[r] = mnew;
            psum[r] = 0.f;
            #pragma unroll
            for (int jt = 0; jt < 4; jt++) {
                p[jt][r] = exp2f(u[jt][r] - mnew);
                psum[r] += p[jt][r];
            }
        }
        #pragma unroll
        for (int off = 1; off <= 8; off <<= 1)
            #pragma unroll
            for (int r = 0; r < 4; r++)
                psum[r] += __shfl_xor(psum[r], off);
        #pragma unroll
        for (int r = 0; r < 4; r++)
            l_run[r] = l_run[r] * alpha[r] + psum[r];

        #pragma unroll
        for (int dt = 0; dt < 4; dt++)
            #pragma unroll
            for (int r = 0; r < 4; r++)
                oacc[dt][r] *= alpha[r];

        // --- P: C-layout regs -> LDS (swizzled) as split bf16 ---
        #pragma unroll
        for (int jt = 0; jt < 4; jt++)
            #pragma unroll
            for (int r = 0; r < 4; r++) {
                const float pv = p[jt][r];
                const ushort_t ph = f2bf(pv);
                const int idx = swz(16 * w + quad * 4 + r, 16 * jt + ln);
                sPh[idx] = ph;
                sPl[idx] = f2bf(pv - bf2f(ph));
            }
        __syncthreads();

        // --- O += P V (split: hh + hl + lh) ---
        #pragma unroll
        for (int kk = 0; kk < 2; kk++) {
            const bf16x8 pfh = *(const bf16x8*)&sPh[swz(16 * w + ln, 32 * kk + quad * 8)];
            const bf16x8 pfl = *(const bf16x8*)&sPl[swz(16 * w + ln, 32 * kk + quad * 8)];
            #pragma unroll
            for (int dt = 0; dt < 4; dt++) {
                const bf16x8 vfh = *(const bf16x8*)&sVh[swz(16 * dt + ln, 32 * kk + quad * 8)];
                const bf16x8 vfl = *(const bf16x8*)&sVl[swz(16 * dt + ln, 32 * kk + quad * 8)];
                oacc[dt] = __builtin_amdgcn_mfma_f32_16x16x32_bf16(pfh, vfh, oacc[dt], 0, 0, 0);
                oacc[dt] = __builtin_amdgcn_mfma_f32_16x16x32_bf16(pfh, vfl, oacc[dt], 0, 0, 0);
                oacc[dt] = __builtin_amdgcn_mfma_f32_16x16x32_bf16(pfl, vfh, oacc[dt], 0, 0, 0);
            }
        }
    }

    // --- epilogue: O / l, write split bf16 ---
    #pragma unroll
    for (int r = 0; r < 4; r++) {
        const float inv_l = 1.f / l_run[r];
        const size_t rowoff = ((size_t)b * L_SEQ + qs + 16 * w + quad * 4 + r) * E_DIM + hoff;
        #pragma unroll
        for (int dt = 0; dt < 4; dt++) {
            const float v = oacc[dt][r] * inv_l;
            const ushort_t vh = f2bf(v);
            outh[rowoff + 16 * dt + ln] = vh;
            outl[rowoff + 16 * dt + ln] = f2bf(v - bf2f(vh));
        }
    }
}

extern "C" void kernel_launch(void* const* d_in, const int* in_sizes, int n_in,
                              void* d_out, int out_size, void* d_ws, size_t ws_size,
                              hipStream_t stream) {
    const float* x         = (const float*)d_in[0];
    const float* in_proj_w = (const float*)d_in[1];
    const float* in_proj_b = (const float*)d_in[2];
    const float* out_w     = (const float*)d_in[3];
    const float* out_b     = (const float*)d_in[4];
    float* out = (float*)d_out;

    const int N = B_SZ * L_SEQ;  // 8192

    char* p = (char*)d_ws;
    ushort_t* xh   = (ushort_t*)p; p += (size_t)N * E_DIM * 2;
    ushort_t* xl   = (ushort_t*)p; p += (size_t)N * E_DIM * 2;
    ushort_t* w1h  = (ushort_t*)p; p += (size_t)3 * E_DIM * E_DIM * 2;
    ushort_t* w1l  = (ushort_t*)p; p += (size_t)3 * E_DIM * E_DIM * 2;
    ushort_t* w2h  = (ushort_t*)p; p += (size_t)E_DIM * E_DIM * 2;
    ushort_t* w2l  = (ushort_t*)p; p += (size_t)E_DIM * E_DIM * 2;
    ushort_t* qkvh = (ushort_t*)p; p += (size_t)N * 3 * E_DIM * 2;
    ushort_t* qkvl = (ushort_t*)p; p += (size_t)N * 3 * E_DIM * 2;
    ushort_t* ath  = (ushort_t*)p; p += (size_t)N * E_DIM * 2;
    ushort_t* atl  = (ushort_t*)p; p += (size_t)N * E_DIM * 2;
    // total = 88,080,384 bytes (same as round 2)

    convert3<<<5120, 256, 0, stream>>>(x, xh, xl, in_proj_w, w1h, w1l, out_w, w2h, w2l);

    gemm_mfma_split<true><<<dim3(64, 12), 256, 0, stream>>>(
        xh, xl, w1h, w1l, in_proj_b, nullptr, qkvh, qkvl, N, 3 * E_DIM, E_DIM);

    attn_mfma<<<dim3(L_SEQ / 64, H_DIM, B_SZ), 256, 0, stream>>>(qkvh, qkvl, ath, atl);

    gemm_mfma_split<false><<<dim3(64, 4), 256, 0, stream>>>(
        ath, atl, w2h, w2l, out_b, out, nullptr, nullptr, N, E_DIM, E_DIM);
}

// Round 4
// 186.243 us; speedup vs baseline: 2.8984x; 1.1594x over previous
//
#include <hip/hip_runtime.h>
#include <math.h>

#define E_DIM 512
#define H_DIM 8
#define WIN 128
#define L_SEQ 4096
#define B_SZ 2
#define QKV_PITCH (3 * E_DIM)

typedef unsigned short ushort_t;
typedef unsigned int uint_t;
typedef __attribute__((ext_vector_type(8))) __bf16 bf16x8;
typedef __attribute__((ext_vector_type(4))) float f32x4;

// ---------- bf16 helpers (manual, RNE) ----------
__device__ __forceinline__ ushort_t f2bf(float f) {
    uint_t u = __float_as_uint(f);
    u = u + 0x7fffu + ((u >> 16) & 1u);
    return (ushort_t)(u >> 16);
}
__device__ __forceinline__ float bf2f(ushort_t h) {
    return __uint_as_float((uint_t)h << 16);
}

__device__ __forceinline__ void gload16(const ushort_t* g, ushort_t* l) {
    __builtin_amdgcn_global_load_lds(
        (const __attribute__((address_space(1))) void*)g,
        (__attribute__((address_space(3))) void*)l,
        16, 0, 0);
}

// ---------- split-convert: fp32 -> (hi, lo) bf16, 3 tensors fused ----------
__global__ __launch_bounds__(256) void convert3(
    const float* __restrict__ x,  ushort_t* __restrict__ xh,  ushort_t* __restrict__ xl,
    const float* __restrict__ w1, ushort_t* __restrict__ w1h, ushort_t* __restrict__ w1l,
    const float* __restrict__ w2, ushort_t* __restrict__ w2h, ushort_t* __restrict__ w2l) {
    int gid = blockIdx.x * 256 + threadIdx.x;
    const float* src; ushort_t* dh; ushort_t* dl; int idx;
    if (gid < 1048576)      { src = x;  dh = xh;  dl = xl;  idx = gid; }
    else if (gid < 1245184) { src = w1; dh = w1h; dl = w1l; idx = gid - 1048576; }
    else                    { src = w2; dh = w2h; dl = w2l; idx = gid - 1245184; }
    float4 v = ((const float4*)src)[idx];
    ushort4 h, l;
    {
        ushort_t a;
        a = f2bf(v.x); h.x = a; l.x = f2bf(v.x - bf2f(a));
        a = f2bf(v.y); h.y = a; l.y = f2bf(v.y - bf2f(a));
        a = f2bf(v.z); h.z = a; l.z = f2bf(v.z - bf2f(a));
        a = f2bf(v.w); h.w = a; l.w = f2bf(v.w - bf2f(a));
    }
    ((ushort4*)dh)[idx] = h;
    ((ushort4*)dl)[idx] = l;
}

// ---------- split-bf16 MFMA GEMM: C = A * W^T + bias ----------
template <bool BF16_OUT>
__global__ __launch_bounds__(256) void gemm_mfma_split(
    const ushort_t* __restrict__ Ah, const ushort_t* __restrict__ Al,
    const ushort_t* __restrict__ Wh, const ushort_t* __restrict__ Wl,
    const float* __restrict__ bias, float* __restrict__ C,
    ushort_t* __restrict__ Ch, ushort_t* __restrict__ Cl,
    int M, int N, int K) {
    __shared__ __align__(16) ushort_t sAh[128 * 32];
    __shared__ __align__(16) ushort_t sAl[128 * 32];
    __shared__ __align__(16) ushort_t sWh[128 * 32];
    __shared__ __align__(16) ushort_t sWl[128 * 32];

    const int tid  = threadIdx.x;
    const int lane = tid & 63;
    const int w    = tid >> 6;
    const int wm   = w & 1, wn = w >> 1;
    const int ln   = lane & 15;
    const int quad = lane >> 4;

    const int srow = 32 * w + (lane >> 2);
    const int skof = (lane & 3) * 8;
    const size_t aoff  = (size_t)(blockIdx.x * 128 + srow) * K + skof;
    const size_t woff  = (size_t)(blockIdx.y * 128 + srow) * K + skof;
    const size_t row16 = (size_t)16 * K;
    const ushort_t* gAh = Ah + aoff;
    const ushort_t* gAl = Al + aoff;
    const ushort_t* gWh = Wh + woff;
    const ushort_t* gWl = Wl + woff;
    const int lbase = (32 * w) * 32;

    f32x4 acc[4][4];
    const f32x4 zero = {0.f, 0.f, 0.f, 0.f};
    #pragma unroll
    for (int i = 0; i < 4; i++)
        #pragma unroll
        for (int j = 0; j < 4; j++) acc[i][j] = zero;

    for (int k0 = 0; k0 < K; k0 += 32) {
        __syncthreads();
        gload16(gAh + k0,         &sAh[lbase]);
        gload16(gAh + k0 + row16, &sAh[lbase + 512]);
        gload16(gAl + k0,         &sAl[lbase]);
        gload16(gAl + k0 + row16, &sAl[lbase + 512]);
        gload16(gWh + k0,         &sWh[lbase]);
        gload16(gWh + k0 + row16, &sWh[lbase + 512]);
        gload16(gWl + k0,         &sWl[lbase]);
        gload16(gWl + k0 + row16, &sWl[lbase + 512]);
        __syncthreads();

        bf16x8 fah[4], fal[4], fbh[4], fbl[4];
        #pragma unroll
        for (int t = 0; t < 4; t++) {
            const int ra = (wm * 64 + t * 16 + ln) * 32 + quad * 8;
            const int rb = (wn * 64 + t * 16 + ln) * 32 + quad * 8;
            fah[t] = *(const bf16x8*)&sAh[ra];
            fal[t] = *(const bf16x8*)&sAl[ra];
            fbh[t] = *(const bf16x8*)&sWh[rb];
            fbl[t] = *(const bf16x8*)&sWl[rb];
        }
        #pragma unroll
        for (int i = 0; i < 4; i++)
            #pragma unroll
            for (int j = 0; j < 4; j++) {
                acc[i][j] = __builtin_amdgcn_mfma_f32_16x16x32_bf16(fah[i], fbh[j], acc[i][j], 0, 0, 0);
                acc[i][j] = __builtin_amdgcn_mfma_f32_16x16x32_bf16(fah[i], fbl[j], acc[i][j], 0, 0, 0);
                acc[i][j] = __builtin_amdgcn_mfma_f32_16x16x32_bf16(fal[i], fbh[j], acc[i][j], 0, 0, 0);
            }
    }

    const int row0 = blockIdx.x * 128 + wm * 64 + quad * 4;
    const int col0 = blockIdx.y * 128 + wn * 64 + ln;
    float bv[4];
    #pragma unroll
    for (int j = 0; j < 4; j++) bv[j] = bias[col0 + j * 16];
    #pragma unroll
    for (int i = 0; i < 4; i++)
        #pragma unroll
        for (int j = 0; j < 4; j++)
            #pragma unroll
            for (int r = 0; r < 4; r++) {
                const size_t idx = (size_t)(row0 + i * 16 + r) * N + col0 + j * 16;
                const float v = acc[i][j][r] + bv[j];
                if (BF16_OUT) {
                    const ushort_t hh = f2bf(v);
                    Ch[idx] = hh;
                    Cl[idx] = f2bf(v - bf2f(hh));
                } else {
                    C[idx] = v;
                }
            }
}

// ---------- MFMA windowed attention v2 ----------
// K: staged via global_load_lds, XOR-swizzled source so unpadded image reads
//    conflict-free as B-fragments. 3-term split QK^T.
// V: hi-only, transposed via 16 coalesced scalar loads + 2 ds_write_b128
//    into pitch-72 region. PV is single-term (P-hi x V-hi); softmax stats fp32.
#define VTP 72
__global__ __launch_bounds__(256) void attn_mfma(
    const ushort_t* __restrict__ qkvh, const ushort_t* __restrict__ qkvl,
    ushort_t* __restrict__ outh, ushort_t* __restrict__ outl) {
    __shared__ __align__(16) ushort_t sKh[64 * 64];
    __shared__ __align__(16) ushort_t sKl[64 * 64];
    __shared__ __align__(16) ushort_t sVt[64 * VTP];
    __shared__ __align__(16) ushort_t sP [64 * VTP];

    const int qs = blockIdx.x * 64;
    const int h = blockIdx.y, b = blockIdx.z;
    const int tid = threadIdx.x, lane = tid & 63;
    const int w = tid >> 6, ln = lane & 15, quad = lane >> 4;

    const size_t bbase = (size_t)b * L_SEQ * QKV_PITCH;
    const int hoff = h * 64;

    // Q fragments (persistent): A-layout [m=ln][k=quad*8+j]
    bf16x8 qf[2][2];
    {
        const size_t qoff = bbase + (size_t)(qs + 16 * w + ln) * QKV_PITCH + hoff + quad * 8;
        qf[0][0] = *(const bf16x8*)(qkvh + qoff);
        qf[1][0] = *(const bf16x8*)(qkvh + qoff + 32);
        qf[0][1] = *(const bf16x8*)(qkvl + qoff);
        qf[1][1] = *(const bf16x8*)(qkvl + qoff + 32);
    }

    // K staging constants: thread t -> LDS slot row (8w + lane>>3), grp lane&7.
    // Source d-group XOR-swizzled by (row&7) = (lane>>3).
    const int st_row  = 8 * w + (lane >> 3);                 // 0..31 per half
    const int st_gsrc = (((lane & 7) ^ (lane >> 3)) << 3);   // element offset
    const ushort_t* kgh = qkvh + bbase + E_DIM + hoff + st_gsrc;
    const ushort_t* kgl = qkvl + bbase + E_DIM + hoff + st_gsrc;
    ushort_t* ldsKh = &sKh[w * 512];
    ushort_t* ldsKl = &sKl[w * 512];

    // V loading: lane = d, wave w covers k-rows 16w..16w+15
    const ushort_t* vg = qkvh + bbase + 2 * E_DIM + hoff + lane;

    f32x4 oacc[4];
    const f32x4 zero = {0.f, 0.f, 0.f, 0.f};
    #pragma unroll
    for (int dt = 0; dt < 4; dt++) oacc[dt] = zero;
    float m_run[4], l_run[4];
    #pragma unroll
    for (int r = 0; r < 4; r++) { m_run[r] = -1e30f; l_run[r] = 0.f; }

    const float cscale = 0.125f * 1.44269504f;  // 1/sqrt(D) * log2(e)

    for (int kt = 0; kt < 5; kt++) {
        const int ks = qs - 128 + kt * 64;

        // --- V^T source rows into regs (coalesced 128B per j) ---
        ushort_t vr[16];
        #pragma unroll
        for (int j = 0; j < 16; j++) {
            int gk = ks + 16 * w + j;
            gk = gk < 0 ? 0 : (gk >= L_SEQ ? L_SEQ - 1 : gk);
            vr[j] = vg[(size_t)gk * QKV_PITCH];
        }

        __syncthreads();  // prev iter done reading sK/sVt/sP

        // --- stage K (hi+lo) via global_load_lds, swizzled source ---
        {
            int r0 = ks + st_row;
            int r1 = ks + 32 + st_row;
            r0 = r0 < 0 ? 0 : (r0 >= L_SEQ ? L_SEQ - 1 : r0);
            r1 = r1 < 0 ? 0 : (r1 >= L_SEQ ? L_SEQ - 1 : r1);
            gload16(kgh + (size_t)r0 * QKV_PITCH, ldsKh);
            gload16(kgh + (size_t)r1 * QKV_PITCH, ldsKh + 2048);
            gload16(kgl + (size_t)r0 * QKV_PITCH, ldsKl);
            gload16(kgl + (size_t)r1 * QKV_PITCH, ldsKl + 2048);
        }

        // --- write V^T (vectorized) ---
        {
            union { ushort_t u[8]; bf16x8 v; } p0, p1;
            #pragma unroll
            for (int j = 0; j < 8; j++) { p0.u[j] = vr[j]; p1.u[j] = vr[8 + j]; }
            *(bf16x8*)&sVt[lane * VTP + 16 * w]     = p0.v;
            *(bf16x8*)&sVt[lane * VTP + 16 * w + 8] = p1.v;
        }

        __syncthreads();  // K staged (barrier drains vmcnt), V^T visible

        // --- S = Q K^T (split: hh + hl + lh), K frags from LDS ---
        f32x4 sacc[4];
        #pragma unroll
        for (int jt = 0; jt < 4; jt++) {
            f32x4 a = zero;
            const bool dead = (kt == 0 && jt < w) || (kt == 4 && jt > w) ||
                              (ks + 16 * jt >= L_SEQ) || (ks + 16 * jt + 15 < 0);
            if (!dead) {
                const int row = 16 * jt + ln;
                const int sw = (row & 7);
                #pragma unroll
                for (int kk = 0; kk < 2; kk++) {
                    const bf16x8 kh = *(const bf16x8*)&sKh[row * 64 + (((4 * kk + quad) ^ sw) << 3)];
                    const bf16x8 kl = *(const bf16x8*)&sKl[row * 64 + (((4 * kk + quad) ^ sw) << 3)];
                    a = __builtin_amdgcn_mfma_f32_16x16x32_bf16(qf[kk][0], kh, a, 0, 0, 0);
                    a = __builtin_amdgcn_mfma_f32_16x16x32_bf16(qf[kk][0], kl, a, 0, 0, 0);
                    a = __builtin_amdgcn_mfma_f32_16x16x32_bf16(qf[kk][1], kh, a, 0, 0, 0);
                }
            }
            sacc[jt] = a;
        }

        // --- mask + online softmax (registers) ---
        float u[4][4];
        #pragma unroll
        for (int jt = 0; jt < 4; jt++) {
            const int kcol = ks + 16 * jt + ln;
            #pragma unroll
            for (int r = 0; r < 4; r++) {
                const int qrow = qs + 16 * w + quad * 4 + r;
                const int dist = qrow > kcol ? qrow - kcol : kcol - qrow;
                const bool ok = (kcol >= 0) && (kcol < L_SEQ) && (dist >= 1) && (dist <= WIN);
                u[jt][r] = ok ? sacc[jt][r] * cscale : -INFINITY;
            }
        }
        float mk[4];
        #pragma unroll
        for (int r = 0; r < 4; r++)
            mk[r] = fmaxf(fmaxf(u[0][r], u[1][r]), fmaxf(u[2][r], u[3][r]));
        #pragma unroll
        for (int off = 1; off <= 8; off <<= 1)
            #pragma unroll
            for (int r = 0; r < 4; r++)
                mk[r] = fmaxf(mk[r], __shfl_xor(mk[r], off));

        float alpha[4], psum[4], p[4][4];
        #pragma unroll
        for (int r = 0; r < 4; r++) {
            const float mnew = fmaxf(fmaxf(m_run[r], mk[r]), -1e30f);
            alpha[r] = exp2f(m_run[r] - mnew);
            m_run[r] = mnew;
            psum[r] = 0.f;
            #pragma unroll
            for (int jt = 0; jt < 4; jt++) {
                p[jt][r] = exp2f(u[jt][r] - mnew);
                psum[r] += p[jt][r];
            }
        }
        #pragma unroll
        for (int off = 1; off <= 8; off <<= 1)
            #pragma unroll
            for (int r = 0; r < 4; r++)
                psum[r] += __shfl_xor(psum[r], off);
        #pragma unroll
        for (int r = 0; r < 4; r++)
            l_run[r] = l_run[r] * alpha[r] + psum[r];

        #pragma unroll
        for (int dt = 0; dt < 4; dt++)
            #pragma unroll
            for (int r = 0; r < 4; r++)
                oacc[dt][r] *= alpha[r];

        // --- P (hi only): C-layout -> LDS A-layout region ---
        #pragma unroll
        for (int jt = 0; jt < 4; jt++)
            #pragma unroll
            for (int r = 0; r < 4; r++)
                sP[(16 * w + quad * 4 + r) * VTP + 16 * jt + ln] = f2bf(p[jt][r]);
        __syncthreads();

        // --- O += P V (single term) ---
        #pragma unroll
        for (int kk = 0; kk < 2; kk++) {
            const bf16x8 pf = *(const bf16x8*)&sP[(16 * w + ln) * VTP + 32 * kk + quad * 8];
            #pragma unroll
            for (int dt = 0; dt < 4; dt++) {
                const bf16x8 vf = *(const bf16x8*)&sVt[(16 * dt + ln) * VTP + 32 * kk + quad * 8];
                oacc[dt] = __builtin_amdgcn_mfma_f32_16x16x32_bf16(pf, vf, oacc[dt], 0, 0, 0);
            }
        }
    }

    // --- epilogue: O / l, write split bf16 ---
    #pragma unroll
    for (int r = 0; r < 4; r++) {
        const float inv_l = 1.f / l_run[r];
        const size_t rowoff = ((size_t)b * L_SEQ + qs + 16 * w + quad * 4 + r) * E_DIM + hoff;
        #pragma unroll
        for (int dt = 0; dt < 4; dt++) {
            const float v = oacc[dt][r] * inv_l;
            const ushort_t vh = f2bf(v);
            outh[rowoff + 16 * dt + ln] = vh;
            outl[rowoff + 16 * dt + ln] = f2bf(v - bf2f(vh));
        }
    }
}

extern "C" void kernel_launch(void* const* d_in, const int* in_sizes, int n_in,
                              void* d_out, int out_size, void* d_ws, size_t ws_size,
                              hipStream_t stream) {
    const float* x         = (const float*)d_in[0];
    const float* in_proj_w = (const float*)d_in[1];
    const float* in_proj_b = (const float*)d_in[2];
    const float* out_w     = (const float*)d_in[3];
    const float* out_b     = (const float*)d_in[4];
    float* out = (float*)d_out;

    const int N = B_SZ * L_SEQ;  // 8192

    char* p = (char*)d_ws;
    ushort_t* xh   = (ushort_t*)p; p += (size_t)N * E_DIM * 2;
    ushort_t* xl   = (ushort_t*)p; p += (size_t)N * E_DIM * 2;
    ushort_t* w1h  = (ushort_t*)p; p += (size_t)3 * E_DIM * E_DIM * 2;
    ushort_t* w1l  = (ushort_t*)p; p += (size_t)3 * E_DIM * E_DIM * 2;
    ushort_t* w2h  = (ushort_t*)p; p += (size_t)E_DIM * E_DIM * 2;
    ushort_t* w2l  = (ushort_t*)p; p += (size_t)E_DIM * E_DIM * 2;
    ushort_t* qkvh = (ushort_t*)p; p += (size_t)N * 3 * E_DIM * 2;
    ushort_t* qkvl = (ushort_t*)p; p += (size_t)N * 3 * E_DIM * 2;
    ushort_t* ath  = (ushort_t*)p; p += (size_t)N * E_DIM * 2;
    ushort_t* atl  = (ushort_t*)p; p += (size_t)N * E_DIM * 2;

    convert3<<<5120, 256, 0, stream>>>(x, xh, xl, in_proj_w, w1h, w1l, out_w, w2h, w2l);

    gemm_mfma_split<true><<<dim3(64, 12), 256, 0, stream>>>(
        xh, xl, w1h, w1l, in_proj_b, nullptr, qkvh, qkvl, N, 3 * E_DIM, E_DIM);

    attn_mfma<<<dim3(L_SEQ / 64, H_DIM, B_SZ), 256, 0, stream>>>(qkvh, qkvl, ath, atl);

    gemm_mfma_split<false><<<dim3(64, 4), 256, 0, stream>>>(
        ath, atl, w2h, w2l, out_b, out, nullptr, nullptr, N, E_DIM, E_DIM);
}

// Round 5
// 178.270 us; speedup vs baseline: 3.0280x; 1.0447x over previous
//
#include <hip/hip_runtime.h>
#include <math.h>

#define E_DIM 512
#define H_DIM 8
#define WIN 128
#define L_SEQ 4096
#define B_SZ 2
#define QKV_PITCH (3 * E_DIM)

typedef unsigned short ushort_t;
typedef unsigned int uint_t;
typedef __attribute__((ext_vector_type(8))) __bf16 bf16x8;
typedef __attribute__((ext_vector_type(4))) float f32x4;

// ---------- bf16 helpers (manual, RNE) ----------
__device__ __forceinline__ ushort_t f2bf(float f) {
    uint_t u = __float_as_uint(f);
    u = u + 0x7fffu + ((u >> 16) & 1u);
    return (ushort_t)(u >> 16);
}
__device__ __forceinline__ float bf2f(ushort_t h) {
    return __uint_as_float((uint_t)h << 16);
}

__device__ __forceinline__ void gload16(const ushort_t* g, ushort_t* l) {
    __builtin_amdgcn_global_load_lds(
        (const __attribute__((address_space(1))) void*)g,
        (__attribute__((address_space(3))) void*)l,
        16, 0, 0);
}

// ===== Tiled fragment-order layout (K=512 for all operands) =====
// element (row, k) -> tile = (row>>4)*16 + (k>>5)
//                     slot = ((k>>3)&3)*16 + (row&15)   [quad*16 + ln]
//                     idx  = tile*512 + slot*8 + (k&7)
// One 16x32 tile = 512 elems = 1024 B = one wave-wide gload16.

// ---------- split-convert into tiled layout ----------
// slot-groups (8 elems): x 524288, w1 98304, w2 32768 -> 655360 total
__global__ __launch_bounds__(256) void convert3(
    const float* __restrict__ x,  ushort_t* __restrict__ xh,  ushort_t* __restrict__ xl,
    const float* __restrict__ w1, ushort_t* __restrict__ w1h, ushort_t* __restrict__ w1l,
    const float* __restrict__ w2, ushort_t* __restrict__ w2h, ushort_t* __restrict__ w2l) {
    int sg = blockIdx.x * 256 + threadIdx.x;
    const float* src; ushort_t* dh; ushort_t* dl;
    if (sg < 524288)      { src = x;  dh = xh;  dl = xl; }
    else if (sg < 622592) { src = w1; dh = w1h; dl = w1l; sg -= 524288; }
    else                  { src = w2; dh = w2h; dl = w2l; sg -= 622592; }
    const int tile = sg >> 6, slot = sg & 63;
    const int row = (tile >> 4) * 16 + (slot & 15);
    const int k   = (tile & 15) * 32 + (slot >> 4) * 8;
    const float4 v0 = *(const float4*)&src[(size_t)row * 512 + k];
    const float4 v1 = *(const float4*)&src[(size_t)row * 512 + k + 4];
    const float vv[8] = {v0.x, v0.y, v0.z, v0.w, v1.x, v1.y, v1.z, v1.w};
    union { ushort_t u[8]; ushort4 v[2]; } h, l;
    #pragma unroll
    for (int j = 0; j < 8; j++) {
        const ushort_t a = f2bf(vv[j]);
        h.u[j] = a;
        l.u[j] = f2bf(vv[j] - bf2f(a));
    }
    ((ushort4*)(dh + (size_t)sg * 8))[0] = h.v[0];
    ((ushort4*)(dh + (size_t)sg * 8))[1] = h.v[1];
    ((ushort4*)(dl + (size_t)sg * 8))[0] = l.v[0];
    ((ushort4*)(dl + (size_t)sg * 8))[1] = l.v[1];
}

// ---------- split-bf16 MFMA GEMM on tiled operands: C = A * W^T + bias ----------
// BM x 128 block tile, BK=32. 4 waves in 2x2 (wave = BM/2 x 64).
template <int BM, bool BF16_OUT>
__global__ __launch_bounds__(256) void gemm_tiled(
    const ushort_t* __restrict__ Ah, const ushort_t* __restrict__ Al,
    const ushort_t* __restrict__ Wh, const ushort_t* __restrict__ Wl,
    const float* __restrict__ bias, float* __restrict__ C,
    ushort_t* __restrict__ Ch, ushort_t* __restrict__ Cl,
    int M, int N, int K) {
    constexpr int MT = BM / 32;   // m-tiles per wave
    constexpr int AT = BM / 16;   // A 16-row tiles per block
    __shared__ __align__(16) ushort_t sAh[AT * 512];
    __shared__ __align__(16) ushort_t sAl[AT * 512];
    __shared__ __align__(16) ushort_t sWh[8 * 512];
    __shared__ __align__(16) ushort_t sWl[8 * 512];

    const int tid = threadIdx.x, lane = tid & 63, w = tid >> 6;
    const int wm = w & 1, wn = w >> 1, ln = lane & 15, quad = lane >> 4;
    const int KT = K >> 5;
    const int lo8 = lane * 8;

    f32x4 acc[MT][4];
    const f32x4 zero = {0.f, 0.f, 0.f, 0.f};
    #pragma unroll
    for (int i = 0; i < MT; i++)
        #pragma unroll
        for (int j = 0; j < 4; j++) acc[i][j] = zero;

    // staging assignment
    const ushort_t* aSrc; ushort_t* aDst; int at0, nA;
    if (BM == 128) {
        aSrc = (w & 2) ? Al : Ah;
        aDst = (w & 2) ? sAl : sAh;
        at0 = (w & 1) * 4; nA = 4;
    } else {
        aSrc = (w & 1) ? Al : Ah;
        aDst = (w & 1) ? sAl : sAh;
        at0 = 0; nA = (w < 2) ? 4 : 0;
    }
    const ushort_t* wSrc = (w & 2) ? Wl : Wh;
    ushort_t* wDst = (w & 2) ? sWl : sWh;
    const int wt0 = (w & 1) * 4;

    const size_t aTileBase = (size_t)blockIdx.x * AT * KT;
    const size_t wTileBase = (size_t)blockIdx.y * 8 * KT;

    for (int kt = 0; kt < KT; kt++) {
        __syncthreads();
        #pragma unroll
        for (int t = 0; t < 4; t++)
            if (t < nA)
                gload16(aSrc + (aTileBase + (size_t)(at0 + t) * KT + kt) * 512 + lo8,
                        &aDst[(at0 + t) * 512]);
        #pragma unroll
        for (int t = 0; t < 4; t++)
            gload16(wSrc + (wTileBase + (size_t)(wt0 + t) * KT + kt) * 512 + lo8,
                    &wDst[(wt0 + t) * 512]);
        __syncthreads();

        bf16x8 fah[MT], fal[MT], fbh[4], fbl[4];
        const int foff = (quad * 16 + ln) * 8;
        #pragma unroll
        for (int i = 0; i < MT; i++) {
            fah[i] = *(const bf16x8*)&sAh[(wm * MT + i) * 512 + foff];
            fal[i] = *(const bf16x8*)&sAl[(wm * MT + i) * 512 + foff];
        }
        #pragma unroll
        for (int j = 0; j < 4; j++) {
            fbh[j] = *(const bf16x8*)&sWh[(wn * 4 + j) * 512 + foff];
            fbl[j] = *(const bf16x8*)&sWl[(wn * 4 + j) * 512 + foff];
        }
        #pragma unroll
        for (int i = 0; i < MT; i++)
            #pragma unroll
            for (int j = 0; j < 4; j++) {
                acc[i][j] = __builtin_amdgcn_mfma_f32_16x16x32_bf16(fah[i], fbh[j], acc[i][j], 0, 0, 0);
                acc[i][j] = __builtin_amdgcn_mfma_f32_16x16x32_bf16(fah[i], fbl[j], acc[i][j], 0, 0, 0);
                acc[i][j] = __builtin_amdgcn_mfma_f32_16x16x32_bf16(fal[i], fbh[j], acc[i][j], 0, 0, 0);
            }
    }

    // epilogue (C row-major): C/D layout col=ln, row=quad*4+r
    #pragma unroll
    for (int i = 0; i < MT; i++) {
        const int row0 = blockIdx.x * BM + (wm * MT + i) * 16 + quad * 4;
        #pragma unroll
        for (int j = 0; j < 4; j++) {
            const int col = blockIdx.y * 128 + (wn * 4 + j) * 16 + ln;
            const float bv = bias[col];
            #pragma unroll
            for (int r = 0; r < 4; r++) {
                const size_t idx = (size_t)(row0 + r) * N + col;
                const float v = acc[i][j][r] + bv;
                if (BF16_OUT) {
                    const ushort_t hh = f2bf(v);
                    Ch[idx] = hh;
                    Cl[idx] = f2bf(v - bf2f(hh));
                } else {
                    C[idx] = v;
                }
            }
        }
    }
}

// ---------- MFMA windowed attention (qkv row-major in, tiled split-bf16 out) ----------
#define VTP 72
__global__ __launch_bounds__(256) void attn_mfma(
    const ushort_t* __restrict__ qkvh, const ushort_t* __restrict__ qkvl,
    ushort_t* __restrict__ outh, ushort_t* __restrict__ outl) {
    __shared__ __align__(16) ushort_t sKh[64 * 64];
    __shared__ __align__(16) ushort_t sKl[64 * 64];
    __shared__ __align__(16) ushort_t sVt[64 * VTP];
    __shared__ __align__(16) ushort_t sP [64 * VTP];

    const int qs = blockIdx.x * 64;
    const int h = blockIdx.y, b = blockIdx.z;
    const int tid = threadIdx.x, lane = tid & 63;
    const int w = tid >> 6, ln = lane & 15, quad = lane >> 4;

    const size_t bbase = (size_t)b * L_SEQ * QKV_PITCH;
    const int hoff = h * 64;

    // Q fragments (persistent): A-layout [m=ln][k=quad*8+j]
    bf16x8 qf[2][2];
    {
        const size_t qoff = bbase + (size_t)(qs + 16 * w + ln) * QKV_PITCH + hoff + quad * 8;
        qf[0][0] = *(const bf16x8*)(qkvh + qoff);
        qf[1][0] = *(const bf16x8*)(qkvh + qoff + 32);
        qf[0][1] = *(const bf16x8*)(qkvl + qoff);
        qf[1][1] = *(const bf16x8*)(qkvl + qoff + 32);
    }

    // K staging: thread -> LDS slot row (8w + lane>>3); source d-group XOR-swizzled
    const int st_row  = 8 * w + (lane >> 3);
    const int st_gsrc = (((lane & 7) ^ (lane >> 3)) << 3);
    const ushort_t* kgh = qkvh + bbase + E_DIM + hoff + st_gsrc;
    const ushort_t* kgl = qkvl + bbase + E_DIM + hoff + st_gsrc;
    ushort_t* ldsKh = &sKh[w * 512];
    ushort_t* ldsKl = &sKl[w * 512];

    // V loading: lane = d, wave w covers k-rows 16w..16w+15
    const ushort_t* vg = qkvh + bbase + 2 * E_DIM + hoff + lane;

    f32x4 oacc[4];
    const f32x4 zero = {0.f, 0.f, 0.f, 0.f};
    #pragma unroll
    for (int dt = 0; dt < 4; dt++) oacc[dt] = zero;
    float m_run[4], l_run[4];
    #pragma unroll
    for (int r = 0; r < 4; r++) { m_run[r] = -1e30f; l_run[r] = 0.f; }

    const float cscale = 0.125f * 1.44269504f;

    for (int kt = 0; kt < 5; kt++) {
        const int ks = qs - 128 + kt * 64;

        // V^T source rows into regs
        ushort_t vr[16];
        #pragma unroll
        for (int j = 0; j < 16; j++) {
            int gk = ks + 16 * w + j;
            gk = gk < 0 ? 0 : (gk >= L_SEQ ? L_SEQ - 1 : gk);
            vr[j] = vg[(size_t)gk * QKV_PITCH];
        }

        __syncthreads();

        // stage K (hi+lo)
        {
            int r0 = ks + st_row;
            int r1 = ks + 32 + st_row;
            r0 = r0 < 0 ? 0 : (r0 >= L_SEQ ? L_SEQ - 1 : r0);
            r1 = r1 < 0 ? 0 : (r1 >= L_SEQ ? L_SEQ - 1 : r1);
            gload16(kgh + (size_t)r0 * QKV_PITCH, ldsKh);
            gload16(kgh + (size_t)r1 * QKV_PITCH, ldsKh + 2048);
            gload16(kgl + (size_t)r0 * QKV_PITCH, ldsKl);
            gload16(kgl + (size_t)r1 * QKV_PITCH, ldsKl + 2048);
        }

        // write V^T
        {
            union { ushort_t u[8]; bf16x8 v; } p0, p1;
            #pragma unroll
            for (int j = 0; j < 8; j++) { p0.u[j] = vr[j]; p1.u[j] = vr[8 + j]; }
            *(bf16x8*)&sVt[lane * VTP + 16 * w]     = p0.v;
            *(bf16x8*)&sVt[lane * VTP + 16 * w + 8] = p1.v;
        }

        __syncthreads();

        // S = Q K^T (hh + hl + lh)
        f32x4 sacc[4];
        #pragma unroll
        for (int jt = 0; jt < 4; jt++) {
            f32x4 a = zero;
            const bool dead = (kt == 0 && jt < w) || (kt == 4 && jt > w) ||
                              (ks + 16 * jt >= L_SEQ) || (ks + 16 * jt + 15 < 0);
            if (!dead) {
                const int row = 16 * jt + ln;
                const int sw = (row & 7);
                #pragma unroll
                for (int kk = 0; kk < 2; kk++) {
                    const bf16x8 kh = *(const bf16x8*)&sKh[row * 64 + (((4 * kk + quad) ^ sw) << 3)];
                    const bf16x8 kl = *(const bf16x8*)&sKl[row * 64 + (((4 * kk + quad) ^ sw) << 3)];
                    a = __builtin_amdgcn_mfma_f32_16x16x32_bf16(qf[kk][0], kh, a, 0, 0, 0);
                    a = __builtin_amdgcn_mfma_f32_16x16x32_bf16(qf[kk][0], kl, a, 0, 0, 0);
                    a = __builtin_amdgcn_mfma_f32_16x16x32_bf16(qf[kk][1], kh, a, 0, 0, 0);
                }
            }
            sacc[jt] = a;
        }

        // mask + online softmax
        float u[4][4];
        #pragma unroll
        for (int jt = 0; jt < 4; jt++) {
            const int kcol = ks + 16 * jt + ln;
            #pragma unroll
            for (int r = 0; r < 4; r++) {
                const int qrow = qs + 16 * w + quad * 4 + r;
                const int dist = qrow > kcol ? qrow - kcol : kcol - qrow;
                const bool ok = (kcol >= 0) && (kcol < L_SEQ) && (dist >= 1) && (dist <= WIN);
                u[jt][r] = ok ? sacc[jt][r] * cscale : -INFINITY;
            }
        }
        float mk[4];
        #pragma unroll
        for (int r = 0; r < 4; r++)
            mk[r] = fmaxf(fmaxf(u[0][r], u[1][r]), fmaxf(u[2][r], u[3][r]));
        #pragma unroll
        for (int off = 1; off <= 8; off <<= 1)
            #pragma unroll
            for (int r = 0; r < 4; r++)
                mk[r] = fmaxf(mk[r], __shfl_xor(mk[r], off));

        float alpha[4], psum[4], p[4][4];
        #pragma unroll
        for (int r = 0; r < 4; r++) {
            const float mnew = fmaxf(fmaxf(m_run[r], mk[r]), -1e30f);
            alpha[r] = exp2f(m_run[r] - mnew);
            m_run[r] = mnew;
            psum[r] = 0.f;
            #pragma unroll
            for (int jt = 0; jt < 4; jt++) {
                p[jt][r] = exp2f(u[jt][r] - mnew);
                psum[r] += p[jt][r];
            }
        }
        #pragma unroll
        for (int off = 1; off <= 8; off <<= 1)
            #pragma unroll
            for (int r = 0; r < 4; r++)
                psum[r] += __shfl_xor(psum[r], off);
        #pragma unroll
        for (int r = 0; r < 4; r++)
            l_run[r] = l_run[r] * alpha[r] + psum[r];

        #pragma unroll
        for (int dt = 0; dt < 4; dt++)
            #pragma unroll
            for (int r = 0; r < 4; r++)
                oacc[dt][r] *= alpha[r];

        // P (hi only) -> LDS A-layout region
        #pragma unroll
        for (int jt = 0; jt < 4; jt++)
            #pragma unroll
            for (int r = 0; r < 4; r++)
                sP[(16 * w + quad * 4 + r) * VTP + 16 * jt + ln] = f2bf(p[jt][r]);
        __syncthreads();

        // O += P V
        #pragma unroll
        for (int kk = 0; kk < 2; kk++) {
            const bf16x8 pf = *(const bf16x8*)&sP[(16 * w + ln) * VTP + 32 * kk + quad * 8];
            #pragma unroll
            for (int dt = 0; dt < 4; dt++) {
                const bf16x8 vf = *(const bf16x8*)&sVt[(16 * dt + ln) * VTP + 32 * kk + quad * 8];
                oacc[dt] = __builtin_amdgcn_mfma_f32_16x16x32_bf16(pf, vf, oacc[dt], 0, 0, 0);
            }
        }
    }

    // epilogue: write split bf16 in tiled fragment-order layout
    // R = b*L + qs + 16w + quad*4 + r ; d = h*64 + dt*16 + ln
    const int Rt = ((b * L_SEQ + qs) >> 4) + w;  // R>>4
    #pragma unroll
    for (int r = 0; r < 4; r++) {
        const float inv_l = 1.f / l_run[r];
        #pragma unroll
        for (int dt = 0; dt < 4; dt++) {
            const float v = oacc[dt][r] * inv_l;
            const ushort_t vh = f2bf(v);
            const int tile = Rt * 16 + h * 2 + (dt >> 1);
            const int slot = ((dt & 1) * 2 + (ln >> 3)) * 16 + quad * 4 + r;
            const size_t idx = (size_t)tile * 512 + slot * 8 + (ln & 7);
            outh[idx] = vh;
            outl[idx] = f2bf(v - bf2f(vh));
        }
    }
}

extern "C" void kernel_launch(void* const* d_in, const int* in_sizes, int n_in,
                              void* d_out, int out_size, void* d_ws, size_t ws_size,
                              hipStream_t stream) {
    const float* x         = (const float*)d_in[0];
    const float* in_proj_w = (const float*)d_in[1];
    const float* in_proj_b = (const float*)d_in[2];
    const float* out_w     = (const float*)d_in[3];
    const float* out_b     = (const float*)d_in[4];
    float* out = (float*)d_out;

    const int N = B_SZ * L_SEQ;  // 8192

    char* p = (char*)d_ws;
    ushort_t* xh   = (ushort_t*)p; p += (size_t)N * E_DIM * 2;
    ushort_t* xl   = (ushort_t*)p; p += (size_t)N * E_DIM * 2;
    ushort_t* w1h  = (ushort_t*)p; p += (size_t)3 * E_DIM * E_DIM * 2;
    ushort_t* w1l  = (ushort_t*)p; p += (size_t)3 * E_DIM * E_DIM * 2;
    ushort_t* w2h  = (ushort_t*)p; p += (size_t)E_DIM * E_DIM * 2;
    ushort_t* w2l  = (ushort_t*)p; p += (size_t)E_DIM * E_DIM * 2;
    ushort_t* qkvh = (ushort_t*)p; p += (size_t)N * 3 * E_DIM * 2;
    ushort_t* qkvl = (ushort_t*)p; p += (size_t)N * 3 * E_DIM * 2;
    ushort_t* ath  = (ushort_t*)p; p += (size_t)N * E_DIM * 2;
    ushort_t* atl  = (ushort_t*)p; p += (size_t)N * E_DIM * 2;

    convert3<<<2560, 256, 0, stream>>>(x, xh, xl, in_proj_w, w1h, w1l, out_w, w2h, w2l);

    gemm_tiled<128, true><<<dim3(64, 12), 256, 0, stream>>>(
        xh, xl, w1h, w1l, in_proj_b, nullptr, qkvh, qkvl, N, 3 * E_DIM, E_DIM);

    attn_mfma<<<dim3(L_SEQ / 64, H_DIM, B_SZ), 256, 0, stream>>>(qkvh, qkvl, ath, atl);

    gemm_tiled<64, false><<<dim3(128, 4), 256, 0, stream>>>(
        ath, atl, w2h, w2l, out_b, out, nullptr, nullptr, N, E_DIM, E_DIM);
}

// Round 6
// 173.075 us; speedup vs baseline: 3.1189x; 1.0300x over previous
//
#include <hip/hip_runtime.h>
#include <math.h>

#define E_DIM 512
#define H_DIM 8
#define WIN 128
#define L_SEQ 4096
#define B_SZ 2
#define QKV_PITCH (3 * E_DIM)

typedef unsigned short ushort_t;
typedef unsigned int uint_t;
typedef __attribute__((ext_vector_type(8))) __bf16 bf16x8;
typedef __attribute__((ext_vector_type(4))) float f32x4;

// ---------- bf16 helpers (manual, RNE) ----------
__device__ __forceinline__ ushort_t f2bf(float f) {
    uint_t u = __float_as_uint(f);
    u = u + 0x7fffu + ((u >> 16) & 1u);
    return (ushort_t)(u >> 16);
}
__device__ __forceinline__ float bf2f(ushort_t h) {
    return __uint_as_float((uint_t)h << 16);
}

__device__ __forceinline__ void gload16(const ushort_t* g, ushort_t* l) {
    __builtin_amdgcn_global_load_lds(
        (const __attribute__((address_space(1))) void*)g,
        (__attribute__((address_space(3))) void*)l,
        16, 0, 0);
}

// ===== Tiled fragment-order layout (K=512 for all operands) =====
// element (row, k) -> tile = (row>>4)*16 + (k>>5)
//                     slot = ((k>>3)&3)*16 + (row&15)   [quad*16 + ln]
//                     idx  = tile*512 + slot*8 + (k&7)
// One 16x32 tile = 512 elems = 1024 B = one wave-wide gload16.

// ---------- split-convert into tiled layout ----------
__global__ __launch_bounds__(256) void convert3(
    const float* __restrict__ x,  ushort_t* __restrict__ xh,  ushort_t* __restrict__ xl,
    const float* __restrict__ w1, ushort_t* __restrict__ w1h, ushort_t* __restrict__ w1l,
    const float* __restrict__ w2, ushort_t* __restrict__ w2h, ushort_t* __restrict__ w2l) {
    int sg = blockIdx.x * 256 + threadIdx.x;
    const float* src; ushort_t* dh; ushort_t* dl;
    if (sg < 524288)      { src = x;  dh = xh;  dl = xl; }
    else if (sg < 622592) { src = w1; dh = w1h; dl = w1l; sg -= 524288; }
    else                  { src = w2; dh = w2h; dl = w2l; sg -= 622592; }
    const int tile = sg >> 6, slot = sg & 63;
    const int row = (tile >> 4) * 16 + (slot & 15);
    const int k   = (tile & 15) * 32 + (slot >> 4) * 8;
    const float4 v0 = *(const float4*)&src[(size_t)row * 512 + k];
    const float4 v1 = *(const float4*)&src[(size_t)row * 512 + k + 4];
    const float vv[8] = {v0.x, v0.y, v0.z, v0.w, v1.x, v1.y, v1.z, v1.w};
    union { ushort_t u[8]; ushort4 v[2]; } h, l;
    #pragma unroll
    for (int j = 0; j < 8; j++) {
        const ushort_t a = f2bf(vv[j]);
        h.u[j] = a;
        l.u[j] = f2bf(vv[j] - bf2f(a));
    }
    ((ushort4*)(dh + (size_t)sg * 8))[0] = h.v[0];
    ((ushort4*)(dh + (size_t)sg * 8))[1] = h.v[1];
    ((ushort4*)(dl + (size_t)sg * 8))[0] = l.v[0];
    ((ushort4*)(dl + (size_t)sg * 8))[1] = l.v[1];
}

// ---------- split-bf16 MFMA GEMM on tiled operands: C = A * W^T + bias ----------
// BM x 128 block tile, BK=32. 4 waves in 2x2 (wave = BM/2 x 64).
// Register-pressure-conscious: A frags resident, B frags loaded per-j;
// staging via wave-uniform tile base pointers (saddr-friendly).
template <int BM, bool BF16_OUT>
__global__ __launch_bounds__(256) void gemm_tiled(
    const ushort_t* __restrict__ Ah, const ushort_t* __restrict__ Al,
    const ushort_t* __restrict__ Wh, const ushort_t* __restrict__ Wl,
    const float* __restrict__ bias, float* __restrict__ C,
    ushort_t* __restrict__ Ch, ushort_t* __restrict__ Cl,
    int M, int N, int K) {
    constexpr int MT = BM / 32;   // m-tiles per wave
    constexpr int AT = BM / 16;   // A 16-row tiles per block
    __shared__ __align__(16) ushort_t sAh[AT * 512];
    __shared__ __align__(16) ushort_t sAl[AT * 512];
    __shared__ __align__(16) ushort_t sWh[8 * 512];
    __shared__ __align__(16) ushort_t sWl[8 * 512];

    const int tid = threadIdx.x, lane = tid & 63, w = tid >> 6;
    const int wm = w & 1, wn = w >> 1, ln = lane & 15, quad = lane >> 4;
    const int KT = K >> 5;
    const int lo8 = lane * 8;

    f32x4 acc[MT][4];
    const f32x4 zero = {0.f, 0.f, 0.f, 0.f};
    #pragma unroll
    for (int i = 0; i < MT; i++)
        #pragma unroll
        for (int j = 0; j < 4; j++) acc[i][j] = zero;

    // staging assignment (wave-uniform)
    const ushort_t* aSrc; ushort_t* aDst; int at0, nA;
    if (BM == 128) {
        aSrc = (w & 2) ? Al : Ah;
        aDst = (w & 2) ? sAl : sAh;
        at0 = (w & 1) * 4; nA = 4;
    } else {
        aSrc = (w & 1) ? Al : Ah;
        aDst = (w & 1) ? sAl : sAh;
        at0 = 0; nA = (w < 2) ? 4 : 0;
    }
    const ushort_t* wSrc = (w & 2) ? Wl : Wh;
    ushort_t* wDst = (w & 2) ? sWl : sWh;
    const int wt0 = (w & 1) * 4;

    // wave-uniform tile base pointers (lane offset added at call site)
    const ushort_t* pa[4];
    const ushort_t* pw[4];
    {
        const size_t aTileBase = (size_t)blockIdx.x * AT * KT;
        const size_t wTileBase = (size_t)blockIdx.y * 8 * KT;
        #pragma unroll
        for (int t = 0; t < 4; t++) {
            pa[t] = aSrc + (aTileBase + (size_t)(at0 + t) * KT) * 512;
            pw[t] = wSrc + (wTileBase + (size_t)(wt0 + t) * KT) * 512;
        }
    }

    for (int kt = 0; kt < KT; kt++) {
        const int koff = kt * 512;
        __syncthreads();
        #pragma unroll
        for (int t = 0; t < 4; t++)
            if (t < nA)
                gload16(pa[t] + koff + lo8, &aDst[(at0 + t) * 512]);
        #pragma unroll
        for (int t = 0; t < 4; t++)
            gload16(pw[t] + koff + lo8, &wDst[(wt0 + t) * 512]);
        __syncthreads();

        const int foff = (quad * 16 + ln) * 8;
        bf16x8 fah[MT], fal[MT];
        #pragma unroll
        for (int i = 0; i < MT; i++) {
            fah[i] = *(const bf16x8*)&sAh[(wm * MT + i) * 512 + foff];
            fal[i] = *(const bf16x8*)&sAl[(wm * MT + i) * 512 + foff];
        }
        #pragma unroll
        for (int j = 0; j < 4; j++) {
            const bf16x8 fbh = *(const bf16x8*)&sWh[(wn * 4 + j) * 512 + foff];
            const bf16x8 fbl = *(const bf16x8*)&sWl[(wn * 4 + j) * 512 + foff];
            #pragma unroll
            for (int i = 0; i < MT; i++) {
                acc[i][j] = __builtin_amdgcn_mfma_f32_16x16x32_bf16(fah[i], fbh, acc[i][j], 0, 0, 0);
                acc[i][j] = __builtin_amdgcn_mfma_f32_16x16x32_bf16(fah[i], fbl, acc[i][j], 0, 0, 0);
                acc[i][j] = __builtin_amdgcn_mfma_f32_16x16x32_bf16(fal[i], fbh, acc[i][j], 0, 0, 0);
            }
        }
    }

    // epilogue (C row-major): C/D layout col=ln, row=quad*4+r
    #pragma unroll
    for (int i = 0; i < MT; i++) {
        const int row0 = blockIdx.x * BM + (wm * MT + i) * 16 + quad * 4;
        #pragma unroll
        for (int j = 0; j < 4; j++) {
            const int col = blockIdx.y * 128 + (wn * 4 + j) * 16 + ln;
            const float bv = bias[col];
            #pragma unroll
            for (int r = 0; r < 4; r++) {
                const size_t idx = (size_t)(row0 + r) * N + col;
                const float v = acc[i][j][r] + bv;
                if (BF16_OUT) {
                    const ushort_t hh = f2bf(v);
                    Ch[idx] = hh;
                    Cl[idx] = f2bf(v - bf2f(hh));
                } else {
                    C[idx] = v;
                }
            }
        }
    }
}

// ---------- MFMA windowed attention (qkv row-major in, tiled split-bf16 out) ----------
#define VTP 72
__global__ __launch_bounds__(256) void attn_mfma(
    const ushort_t* __restrict__ qkvh, const ushort_t* __restrict__ qkvl,
    ushort_t* __restrict__ outh, ushort_t* __restrict__ outl) {
    __shared__ __align__(16) ushort_t sKh[64 * 64];
    __shared__ __align__(16) ushort_t sKl[64 * 64];
    __shared__ __align__(16) ushort_t sVt[64 * VTP];
    __shared__ __align__(16) ushort_t sP [64 * VTP];

    const int qs = blockIdx.x * 64;
    const int h = blockIdx.y, b = blockIdx.z;
    const int tid = threadIdx.x, lane = tid & 63;
    const int w = tid >> 6, ln = lane & 15, quad = lane >> 4;

    const size_t bbase = (size_t)b * L_SEQ * QKV_PITCH;
    const int hoff = h * 64;

    // Q fragments (persistent): A-layout [m=ln][k=quad*8+j]
    bf16x8 qf[2][2];
    {
        const size_t qoff = bbase + (size_t)(qs + 16 * w + ln) * QKV_PITCH + hoff + quad * 8;
        qf[0][0] = *(const bf16x8*)(qkvh + qoff);
        qf[1][0] = *(const bf16x8*)(qkvh + qoff + 32);
        qf[0][1] = *(const bf16x8*)(qkvl + qoff);
        qf[1][1] = *(const bf16x8*)(qkvl + qoff + 32);
    }

    // K staging: thread -> LDS slot row (8w + lane>>3); source d-group XOR-swizzled
    const int st_row  = 8 * w + (lane >> 3);
    const int st_gsrc = (((lane & 7) ^ (lane >> 3)) << 3);
    const ushort_t* kgh = qkvh + bbase + E_DIM + hoff + st_gsrc;
    const ushort_t* kgl = qkvl + bbase + E_DIM + hoff + st_gsrc;
    ushort_t* ldsKh = &sKh[w * 512];
    ushort_t* ldsKl = &sKl[w * 512];

    // V loading: lane = d, wave w covers k-rows 16w..16w+15
    const ushort_t* vg = qkvh + bbase + 2 * E_DIM + hoff + lane;

    f32x4 oacc[4];
    const f32x4 zero = {0.f, 0.f, 0.f, 0.f};
    #pragma unroll
    for (int dt = 0; dt < 4; dt++) oacc[dt] = zero;
    float m_run[4], l_run[4];
    #pragma unroll
    for (int r = 0; r < 4; r++) { m_run[r] = -1e30f; l_run[r] = 0.f; }

    const float cscale = 0.125f * 1.44269504f;

    for (int kt = 0; kt < 5; kt++) {
        const int ks = qs - 128 + kt * 64;

        // V^T source rows into regs
        ushort_t vr[16];
        #pragma unroll
        for (int j = 0; j < 16; j++) {
            int gk = ks + 16 * w + j;
            gk = gk < 0 ? 0 : (gk >= L_SEQ ? L_SEQ - 1 : gk);
            vr[j] = vg[(size_t)gk * QKV_PITCH];
        }

        __syncthreads();

        // stage K (hi+lo)
        {
            int r0 = ks + st_row;
            int r1 = ks + 32 + st_row;
            r0 = r0 < 0 ? 0 : (r0 >= L_SEQ ? L_SEQ - 1 : r0);
            r1 = r1 < 0 ? 0 : (r1 >= L_SEQ ? L_SEQ - 1 : r1);
            gload16(kgh + (size_t)r0 * QKV_PITCH, ldsKh);
            gload16(kgh + (size_t)r1 * QKV_PITCH, ldsKh + 2048);
            gload16(kgl + (size_t)r0 * QKV_PITCH, ldsKl);
            gload16(kgl + (size_t)r1 * QKV_PITCH, ldsKl + 2048);
        }

        // write V^T
        {
            union { ushort_t u[8]; bf16x8 v; } p0, p1;
            #pragma unroll
            for (int j = 0; j < 8; j++) { p0.u[j] = vr[j]; p1.u[j] = vr[8 + j]; }
            *(bf16x8*)&sVt[lane * VTP + 16 * w]     = p0.v;
            *(bf16x8*)&sVt[lane * VTP + 16 * w + 8] = p1.v;
        }

        __syncthreads();

        // S = Q K^T (hh + hl + lh)
        f32x4 sacc[4];
        #pragma unroll
        for (int jt = 0; jt < 4; jt++) {
            f32x4 a = zero;
            const bool dead = (kt == 0 && jt < w) || (kt == 4 && jt > w) ||
                              (ks + 16 * jt >= L_SEQ) || (ks + 16 * jt + 15 < 0);
            if (!dead) {
                const int row = 16 * jt + ln;
                const int sw = (row & 7);
                #pragma unroll
                for (int kk = 0; kk < 2; kk++) {
                    const bf16x8 kh = *(const bf16x8*)&sKh[row * 64 + (((4 * kk + quad) ^ sw) << 3)];
                    const bf16x8 kl = *(const bf16x8*)&sKl[row * 64 + (((4 * kk + quad) ^ sw) << 3)];
                    a = __builtin_amdgcn_mfma_f32_16x16x32_bf16(qf[kk][0], kh, a, 0, 0, 0);
                    a = __builtin_amdgcn_mfma_f32_16x16x32_bf16(qf[kk][0], kl, a, 0, 0, 0);
                    a = __builtin_amdgcn_mfma_f32_16x16x32_bf16(qf[kk][1], kh, a, 0, 0, 0);
                }
            }
            sacc[jt] = a;
        }

        // mask + online softmax
        float u[4][4];
        #pragma unroll
        for (int jt = 0; jt < 4; jt++) {
            const int kcol = ks + 16 * jt + ln;
            #pragma unroll
            for (int r = 0; r < 4; r++) {
                const int qrow = qs + 16 * w + quad * 4 + r;
                const int dist = qrow > kcol ? qrow - kcol : kcol - qrow;
                const bool ok = (kcol >= 0) && (kcol < L_SEQ) && (dist >= 1) && (dist <= WIN);
                u[jt][r] = ok ? sacc[jt][r] * cscale : -INFINITY;
            }
        }
        float mk[4];
        #pragma unroll
        for (int r = 0; r < 4; r++)
            mk[r] = fmaxf(fmaxf(u[0][r], u[1][r]), fmaxf(u[2][r], u[3][r]));
        #pragma unroll
        for (int off = 1; off <= 8; off <<= 1)
            #pragma unroll
            for (int r = 0; r < 4; r++)
                mk[r] = fmaxf(mk[r], __shfl_xor(mk[r], off));

        float alpha[4], psum[4], p[4][4];
        #pragma unroll
        for (int r = 0; r < 4; r++) {
            const float mnew = fmaxf(fmaxf(m_run[r], mk[r]), -1e30f);
            alpha[r] = exp2f(m_run[r] - mnew);
            m_run[r] = mnew;
            psum[r] = 0.f;
            #pragma unroll
            for (int jt = 0; jt < 4; jt++) {
                p[jt][r] = exp2f(u[jt][r] - mnew);
                psum[r] += p[jt][r];
            }
        }
        #pragma unroll
        for (int off = 1; off <= 8; off <<= 1)
            #pragma unroll
            for (int r = 0; r < 4; r++)
                psum[r] += __shfl_xor(psum[r], off);
        #pragma unroll
        for (int r = 0; r < 4; r++)
            l_run[r] = l_run[r] * alpha[r] + psum[r];

        #pragma unroll
        for (int dt = 0; dt < 4; dt++)
            #pragma unroll
            for (int r = 0; r < 4; r++)
                oacc[dt][r] *= alpha[r];

        // P (hi only) -> LDS A-layout region
        #pragma unroll
        for (int jt = 0; jt < 4; jt++)
            #pragma unroll
            for (int r = 0; r < 4; r++)
                sP[(16 * w + quad * 4 + r) * VTP + 16 * jt + ln] = f2bf(p[jt][r]);
        __syncthreads();

        // O += P V
        #pragma unroll
        for (int kk = 0; kk < 2; kk++) {
            const bf16x8 pf = *(const bf16x8*)&sP[(16 * w + ln) * VTP + 32 * kk + quad * 8];
            #pragma unroll
            for (int dt = 0; dt < 4; dt++) {
                const bf16x8 vf = *(const bf16x8*)&sVt[(16 * dt + ln) * VTP + 32 * kk + quad * 8];
                oacc[dt] = __builtin_amdgcn_mfma_f32_16x16x32_bf16(pf, vf, oacc[dt], 0, 0, 0);
            }
        }
    }

    // epilogue: write split bf16 in tiled fragment-order layout
    const int Rt = ((b * L_SEQ + qs) >> 4) + w;  // R>>4
    #pragma unroll
    for (int r = 0; r < 4; r++) {
        const float inv_l = 1.f / l_run[r];
        #pragma unroll
        for (int dt = 0; dt < 4; dt++) {
            const float v = oacc[dt][r] * inv_l;
            const ushort_t vh = f2bf(v);
            const int tile = Rt * 16 + h * 2 + (dt >> 1);
            const int slot = ((dt & 1) * 2 + (ln >> 3)) * 16 + quad * 4 + r;
            const size_t idx = (size_t)tile * 512 + slot * 8 + (ln & 7);
            outh[idx] = vh;
            outl[idx] = f2bf(v - bf2f(vh));
        }
    }
}

extern "C" void kernel_launch(void* const* d_in, const int* in_sizes, int n_in,
                              void* d_out, int out_size, void* d_ws, size_t ws_size,
                              hipStream_t stream) {
    const float* x         = (const float*)d_in[0];
    const float* in_proj_w = (const float*)d_in[1];
    const float* in_proj_b = (const float*)d_in[2];
    const float* out_w     = (const float*)d_in[3];
    const float* out_b     = (const float*)d_in[4];
    float* out = (float*)d_out;

    const int N = B_SZ * L_SEQ;  // 8192

    char* p = (char*)d_ws;
    ushort_t* xh   = (ushort_t*)p; p += (size_t)N * E_DIM * 2;
    ushort_t* xl   = (ushort_t*)p; p += (size_t)N * E_DIM * 2;
    ushort_t* w1h  = (ushort_t*)p; p += (size_t)3 * E_DIM * E_DIM * 2;
    ushort_t* w1l  = (ushort_t*)p; p += (size_t)3 * E_DIM * E_DIM * 2;
    ushort_t* w2h  = (ushort_t*)p; p += (size_t)E_DIM * E_DIM * 2;
    ushort_t* w2l  = (ushort_t*)p; p += (size_t)E_DIM * E_DIM * 2;
    ushort_t* qkvh = (ushort_t*)p; p += (size_t)N * 3 * E_DIM * 2;
    ushort_t* qkvl = (ushort_t*)p; p += (size_t)N * 3 * E_DIM * 2;
    ushort_t* ath  = (ushort_t*)p; p += (size_t)N * E_DIM * 2;
    ushort_t* atl  = (ushort_t*)p; p += (size_t)N * E_DIM * 2;

    convert3<<<2560, 256, 0, stream>>>(x, xh, xl, in_proj_w, w1h, w1l, out_w, w2h, w2l);

    gemm_tiled<128, true><<<dim3(64, 12), 256, 0, stream>>>(
        xh, xl, w1h, w1l, in_proj_b, nullptr, qkvh, qkvl, N, 3 * E_DIM, E_DIM);

    attn_mfma<<<dim3(L_SEQ / 64, H_DIM, B_SZ), 256, 0, stream>>>(qkvh, qkvl, ath, atl);

    gemm_tiled<64, false><<<dim3(128, 4), 256, 0, stream>>>(
        ath, atl, w2h, w2l, out_b, out, nullptr, nullptr, N, E_DIM, E_DIM);
}

// Round 7
// 171.231 us; speedup vs baseline: 3.1525x; 1.0108x over previous
//
#include <hip/hip_runtime.h>
#include <math.h>

#define E_DIM 512
#define H_DIM 8
#define WIN 128
#define L_SEQ 4096
#define B_SZ 2

typedef unsigned short ushort_t;
typedef unsigned int uint_t;
typedef __attribute__((ext_vector_type(8))) __bf16 bf16x8;
typedef __attribute__((ext_vector_type(4))) float f32x4;

// ---------- bf16 helpers (manual, RNE) ----------
__device__ __forceinline__ ushort_t f2bf(float f) {
    uint_t u = __float_as_uint(f);
    u = u + 0x7fffu + ((u >> 16) & 1u);
    return (ushort_t)(u >> 16);
}
__device__ __forceinline__ float bf2f(ushort_t h) {
    return __uint_as_float((uint_t)h << 16);
}

__device__ __forceinline__ void gload16(const ushort_t* g, ushort_t* l) {
    __builtin_amdgcn_global_load_lds(
        (const __attribute__((address_space(1))) void*)g,
        (__attribute__((address_space(3))) void*)l,
        16, 0, 0);
}

// ===== Tile image (16 rows x 32 k = 512 elems = 1 KB) =====
// idx = slot*8 + (k&7), slot = ((k>>3)&3)*16 + (row&15)
// A-frag & B-frag both read at lane*8 within a tile image.

// ---------- split-convert into tiled layout (x, w1, w2; all K=512) ----------
__global__ __launch_bounds__(256) void convert3(
    const float* __restrict__ x,  ushort_t* __restrict__ xh,  ushort_t* __restrict__ xl,
    const float* __restrict__ w1, ushort_t* __restrict__ w1h, ushort_t* __restrict__ w1l,
    const float* __restrict__ w2, ushort_t* __restrict__ w2h, ushort_t* __restrict__ w2l) {
    int sg = blockIdx.x * 256 + threadIdx.x;
    const float* src; ushort_t* dh; ushort_t* dl;
    if (sg < 524288)      { src = x;  dh = xh;  dl = xl; }
    else if (sg < 622592) { src = w1; dh = w1h; dl = w1l; sg -= 524288; }
    else                  { src = w2; dh = w2h; dl = w2l; sg -= 622592; }
    const int tile = sg >> 6, slot = sg & 63;
    const int row = (tile >> 4) * 16 + (slot & 15);
    const int k   = (tile & 15) * 32 + (slot >> 4) * 8;
    const float4 v0 = *(const float4*)&src[(size_t)row * 512 + k];
    const float4 v1 = *(const float4*)&src[(size_t)row * 512 + k + 4];
    const float vv[8] = {v0.x, v0.y, v0.z, v0.w, v1.x, v1.y, v1.z, v1.w};
    union { ushort_t u[8]; ushort4 v[2]; } h, l;
    #pragma unroll
    for (int j = 0; j < 8; j++) {
        const ushort_t a = f2bf(vv[j]);
        h.u[j] = a;
        l.u[j] = f2bf(vv[j] - bf2f(a));
    }
    ((ushort4*)(dh + (size_t)sg * 8))[0] = h.v[0];
    ((ushort4*)(dh + (size_t)sg * 8))[1] = h.v[1];
    ((ushort4*)(dl + (size_t)sg * 8))[0] = l.v[0];
    ((ushort4*)(dl + (size_t)sg * 8))[1] = l.v[1];
}

// ---------- GEMM1: qkv projection, epilogue writes attention-ready layouts ----
// 128x128 tile, BK=32, grid (64, 12). by<4: q, by in [4,8): k, by>=8: v.
// q: A-frag tiles [bh][qtile 256][kt 2];  k: B-frag tiles [bh][ktile 256][kt 2];
// v: transposed B-frag tiles [bh][kwin 64][dt 4][kk 2], hi only.
__global__ __launch_bounds__(256) void gemm_qkv(
    const ushort_t* __restrict__ Ah, const ushort_t* __restrict__ Al,
    const ushort_t* __restrict__ Wh, const ushort_t* __restrict__ Wl,
    const float* __restrict__ bias,
    ushort_t* __restrict__ qTh, ushort_t* __restrict__ qTl,
    ushort_t* __restrict__ kTh, ushort_t* __restrict__ kTl,
    ushort_t* __restrict__ vTh) {
    __shared__ __align__(16) ushort_t sAh[8 * 512];
    __shared__ __align__(16) ushort_t sAl[8 * 512];
    __shared__ __align__(16) ushort_t sWh[8 * 512];
    __shared__ __align__(16) ushort_t sWl[8 * 512];

    const int tid = threadIdx.x, lane = tid & 63, w = tid >> 6;
    const int wm = w & 1, wn = w >> 1, ln = lane & 15, quad = lane >> 4;
    const int bx = blockIdx.x, by = blockIdx.y;
    const int lo8 = lane * 8;

    f32x4 acc[4][4];
    const f32x4 zero = {0.f, 0.f, 0.f, 0.f};
    #pragma unroll
    for (int i = 0; i < 4; i++)
        #pragma unroll
        for (int j = 0; j < 4; j++) acc[i][j] = zero;

    const ushort_t* aSrc = (w & 2) ? Al : Ah;
    ushort_t* aDst = (w & 2) ? sAl : sAh;
    const ushort_t* wSrc = (w & 2) ? Wl : Wh;
    ushort_t* wDst = (w & 2) ? sWl : sWh;
    const int at0 = (w & 1) * 4, wt0 = (w & 1) * 4;

    const ushort_t* pa[4];
    const ushort_t* pw[4];
    #pragma unroll
    for (int t = 0; t < 4; t++) {
        pa[t] = aSrc + ((size_t)(bx * 8 + at0 + t) * 16) * 512;
        pw[t] = wSrc + ((size_t)(by * 8 + wt0 + t) * 16) * 512;
    }

    for (int kt = 0; kt < 16; kt++) {
        const int koff = kt * 512;
        __syncthreads();
        #pragma unroll
        for (int t = 0; t < 4; t++)
            gload16(pa[t] + koff + lo8, &aDst[(at0 + t) * 512]);
        #pragma unroll
        for (int t = 0; t < 4; t++)
            gload16(pw[t] + koff + lo8, &wDst[(wt0 + t) * 512]);
        __syncthreads();

        const int foff = lo8;
        bf16x8 fah[4], fal[4];
        #pragma unroll
        for (int i = 0; i < 4; i++) {
            fah[i] = *(const bf16x8*)&sAh[(wm * 4 + i) * 512 + foff];
            fal[i] = *(const bf16x8*)&sAl[(wm * 4 + i) * 512 + foff];
        }
        #pragma unroll
        for (int j = 0; j < 4; j++) {
            const bf16x8 fbh = *(const bf16x8*)&sWh[(wn * 4 + j) * 512 + foff];
            const bf16x8 fbl = *(const bf16x8*)&sWl[(wn * 4 + j) * 512 + foff];
            #pragma unroll
            for (int i = 0; i < 4; i++) {
                acc[i][j] = __builtin_amdgcn_mfma_f32_16x16x32_bf16(fah[i], fbh, acc[i][j], 0, 0, 0);
                acc[i][j] = __builtin_amdgcn_mfma_f32_16x16x32_bf16(fah[i], fbl, acc[i][j], 0, 0, 0);
                acc[i][j] = __builtin_amdgcn_mfma_f32_16x16x32_bf16(fal[i], fbh, acc[i][j], 0, 0, 0);
            }
        }
    }

    // ---- epilogue: C/D layout col=ln (within j-tile), row=quad*4+r ----
    const int b = bx >> 5;               // batch
    const int h = 2 * (by & 3) + wn;     // head (wave-uniform)
    if (by < 8) {
        ushort_t* dh = (by < 4) ? qTh : kTh;
        ushort_t* dl = (by < 4) ? qTl : kTl;
        #pragma unroll
        for (int i = 0; i < 4; i++) {
            const int rt = (bx & 31) * 8 + wm * 4 + i;   // row-tile within batch
            const size_t tb = ((size_t)(b * 8 + h) * 256 + rt) * 2;
            #pragma unroll
            for (int j = 0; j < 4; j++) {
                const float bv = bias[by * 128 + wn * 64 + j * 16 + ln];
                const size_t tile = tb + (j >> 1);
                #pragma unroll
                for (int r = 0; r < 4; r++) {
                    const int slot = ((j * 2 + (ln >> 3)) & 3) * 16 + quad * 4 + r;
                    const size_t idx = tile * 512 + slot * 8 + (ln & 7);
                    const float v = acc[i][j][r] + bv;
                    const ushort_t hh = f2bf(v);
                    dh[idx] = hh;
                    dl[idx] = f2bf(v - bf2f(hh));
                }
            }
        }
    } else {
        // v: hi only, transposed tiles (rows = d, k = kseq)
        const int kwin = (bx & 31) * 2 + wm;
        #pragma unroll
        for (int i = 0; i < 4; i++) {
            const int kk = i >> 1;
            #pragma unroll
            for (int j = 0; j < 4; j++) {
                const float bv = bias[by * 128 + wn * 64 + j * 16 + ln];
                const size_t tile = (((size_t)(b * 8 + h) * 64 + kwin) * 4 + j) * 2 + kk;
                #pragma unroll
                for (int r = 0; r < 4; r++) {
                    const int klq = quad * 4 + r;
                    const int slot = ((i & 1) * 2 + (klq >> 3)) * 16 + ln;
                    const size_t idx = tile * 512 + slot * 8 + (klq & 7);
                    vTh[idx] = f2bf(acc[i][j][r] + bv);
                }
            }
        }
    }
}

// ---------- MFMA windowed attention: all operands pre-tiled ----------
__global__ __launch_bounds__(256) void attn_mfma(
    const ushort_t* __restrict__ qTh, const ushort_t* __restrict__ qTl,
    const ushort_t* __restrict__ kTh, const ushort_t* __restrict__ kTl,
    const ushort_t* __restrict__ vTh,
    ushort_t* __restrict__ outh, ushort_t* __restrict__ outl) {
    __shared__ __align__(16) ushort_t sKh[8 * 512];
    __shared__ __align__(16) ushort_t sKl[8 * 512];
    __shared__ __align__(16) ushort_t sV [8 * 512];
    __shared__ __align__(16) ushort_t sP [8 * 512];

    const int qs = blockIdx.x * 64;
    const int h = blockIdx.y, b = blockIdx.z;
    const int tid = threadIdx.x, lane = tid & 63;
    const int w = tid >> 6, ln = lane & 15, quad = lane >> 4;
    const int bh = b * 8 + h;
    const int lo8 = lane * 8;

    // Q fragments: direct global loads from A-frag tiles
    bf16x8 qf[2][2];
    {
        const size_t qt = ((size_t)bh * 256 + (qs >> 4) + w) * 2;
        qf[0][0] = *(const bf16x8*)(qTh + (qt + 0) * 512 + lo8);
        qf[1][0] = *(const bf16x8*)(qTh + (qt + 1) * 512 + lo8);
        qf[0][1] = *(const bf16x8*)(qTl + (qt + 0) * 512 + lo8);
        qf[1][1] = *(const bf16x8*)(qTl + (qt + 1) * 512 + lo8);
    }

    f32x4 oacc[4];
    const f32x4 zero = {0.f, 0.f, 0.f, 0.f};
    #pragma unroll
    for (int dt = 0; dt < 4; dt++) oacc[dt] = zero;
    float m_run[4], l_run[4];
    #pragma unroll
    for (int r = 0; r < 4; r++) { m_run[r] = -1e30f; l_run[r] = 0.f; }

    const float cscale = 0.125f * 1.44269504f;  // 1/sqrt(D) * log2(e)

    for (int kt = 0; kt < 5; kt++) {
        const int ks = qs - 128 + kt * 64;

        __syncthreads();  // prev iter's MFMA reads of sK/sV/sP done

        // stage K (jt = w) and V (dt = w), clamped tile indices
        {
            int st = (qs >> 4) - 8 + kt * 4 + w;
            st = st < 0 ? 0 : (st > 255 ? 255 : st);
            const size_t kb = ((size_t)bh * 256 + st) * 2 * 512 + lo8;
            gload16(kTh + kb,       &sKh[(w * 2 + 0) * 512]);
            gload16(kTh + kb + 512, &sKh[(w * 2 + 1) * 512]);
            gload16(kTl + kb,       &sKl[(w * 2 + 0) * 512]);
            gload16(kTl + kb + 512, &sKl[(w * 2 + 1) * 512]);
            int vw = (qs >> 6) - 2 + kt;
            vw = vw < 0 ? 0 : (vw > 63 ? 63 : vw);
            const size_t vb = (((size_t)bh * 64 + vw) * 4 + w) * 2 * 512 + lo8;
            gload16(vTh + vb,       &sV[(w * 2 + 0) * 512]);
            gload16(vTh + vb + 512, &sV[(w * 2 + 1) * 512]);
        }
        __syncthreads();  // staging visible

        // S = Q K^T (hh + hl + lh)
        f32x4 sacc[4];
        #pragma unroll
        for (int jt = 0; jt < 4; jt++) {
            f32x4 a = zero;
            const bool dead = (kt == 0 && jt < w) || (kt == 4 && jt > w) ||
                              (ks + 16 * jt >= L_SEQ) || (ks + 16 * jt + 15 < 0);
            if (!dead) {
                #pragma unroll
                for (int kk = 0; kk < 2; kk++) {
                    const bf16x8 kh = *(const bf16x8*)&sKh[(jt * 2 + kk) * 512 + lo8];
                    const bf16x8 klo = *(const bf16x8*)&sKl[(jt * 2 + kk) * 512 + lo8];
                    a = __builtin_amdgcn_mfma_f32_16x16x32_bf16(qf[kk][0], kh, a, 0, 0, 0);
                    a = __builtin_amdgcn_mfma_f32_16x16x32_bf16(qf[kk][0], klo, a, 0, 0, 0);
                    a = __builtin_amdgcn_mfma_f32_16x16x32_bf16(qf[kk][1], kh, a, 0, 0, 0);
                }
            }
            sacc[jt] = a;
        }

        // mask + online softmax (registers)
        float u[4][4];
        #pragma unroll
        for (int jt = 0; jt < 4; jt++) {
            const int kcol = ks + 16 * jt + ln;
            #pragma unroll
            for (int r = 0; r < 4; r++) {
                const int qrow = qs + 16 * w + quad * 4 + r;
                const int dist = qrow > kcol ? qrow - kcol : kcol - qrow;
                const bool ok = (kcol >= 0) && (kcol < L_SEQ) && (dist >= 1) && (dist <= WIN);
                u[jt][r] = ok ? sacc[jt][r] * cscale : -INFINITY;
            }
        }
        float mk[4];
        #pragma unroll
        for (int r = 0; r < 4; r++)
            mk[r] = fmaxf(fmaxf(u[0][r], u[1][r]), fmaxf(u[2][r], u[3][r]));
        #pragma unroll
        for (int off = 1; off <= 8; off <<= 1)
            #pragma unroll
            for (int r = 0; r < 4; r++)
                mk[r] = fmaxf(mk[r], __shfl_xor(mk[r], off));

        float alpha[4], psum[4], p[4][4];
        #pragma unroll
        for (int r = 0; r < 4; r++) {
            const float mnew = fmaxf(fmaxf(m_run[r], mk[r]), -1e30f);
            alpha[r] = exp2f(m_run[r] - mnew);
            m_run[r] = mnew;
            psum[r] = 0.f;
            #pragma unroll
            for (int jt = 0; jt < 4; jt++) {
                p[jt][r] = exp2f(u[jt][r] - mnew);
                psum[r] += p[jt][r];
            }
        }
        #pragma unroll
        for (int off = 1; off <= 8; off <<= 1)
            #pragma unroll
            for (int r = 0; r < 4; r++)
                psum[r] += __shfl_xor(psum[r], off);
        #pragma unroll
        for (int r = 0; r < 4; r++)
            l_run[r] = l_run[r] * alpha[r] + psum[r];

        #pragma unroll
        for (int dt = 0; dt < 4; dt++)
            #pragma unroll
            for (int r = 0; r < 4; r++)
                oacc[dt][r] *= alpha[r];

        // P (hi only): C-layout regs -> own wave's A-frag tile images in LDS
        #pragma unroll
        for (int jt = 0; jt < 4; jt++)
            #pragma unroll
            for (int r = 0; r < 4; r++) {
                const int slot = ((jt & 1) * 2 + (ln >> 3)) * 16 + quad * 4 + r;
                sP[w * 1024 + (jt >> 1) * 512 + slot * 8 + (ln & 7)] = f2bf(p[jt][r]);
            }
        // no barrier needed: PV reads only this wave's sP region + sV (staged pre-barrier)

        // O += P V (hi x hi)
        #pragma unroll
        for (int kk = 0; kk < 2; kk++) {
            const bf16x8 pf = *(const bf16x8*)&sP[w * 1024 + kk * 512 + lo8];
            #pragma unroll
            for (int dt = 0; dt < 4; dt++) {
                const bf16x8 vf = *(const bf16x8*)&sV[(dt * 2 + kk) * 512 + lo8];
                oacc[dt] = __builtin_amdgcn_mfma_f32_16x16x32_bf16(pf, vf, oacc[dt], 0, 0, 0);
            }
        }
    }

    // epilogue: write split bf16 in GEMM2's A-frag tiled layout
    const int Rt = ((b * L_SEQ + qs) >> 4) + w;
    #pragma unroll
    for (int r = 0; r < 4; r++) {
        const float inv_l = 1.f / l_run[r];
        #pragma unroll
        for (int dt = 0; dt < 4; dt++) {
            const float v = oacc[dt][r] * inv_l;
            const ushort_t vh = f2bf(v);
            const int tile = Rt * 16 + h * 2 + (dt >> 1);
            const int slot = ((dt & 1) * 2 + (ln >> 3)) * 16 + quad * 4 + r;
            const size_t idx = (size_t)tile * 512 + slot * 8 + (ln & 7);
            outh[idx] = vh;
            outl[idx] = f2bf(v - bf2f(vh));
        }
    }
}

// ---------- GEMM2: out projection, 64x64 tile, grid (128, 8) ----------
__global__ __launch_bounds__(256) void gemm_out(
    const ushort_t* __restrict__ Ah, const ushort_t* __restrict__ Al,
    const ushort_t* __restrict__ Wh, const ushort_t* __restrict__ Wl,
    const float* __restrict__ bias, float* __restrict__ C) {
    __shared__ __align__(16) ushort_t sAh[4 * 512];
    __shared__ __align__(16) ushort_t sAl[4 * 512];
    __shared__ __align__(16) ushort_t sWh[4 * 512];
    __shared__ __align__(16) ushort_t sWl[4 * 512];

    const int tid = threadIdx.x, lane = tid & 63, w = tid >> 6;
    const int wm = w & 1, wn = w >> 1, ln = lane & 15, quad = lane >> 4;
    const int bx = blockIdx.x, by = blockIdx.y;
    const int lo8 = lane * 8;

    f32x4 acc[2][2];
    const f32x4 zero = {0.f, 0.f, 0.f, 0.f};
    #pragma unroll
    for (int i = 0; i < 2; i++)
        #pragma unroll
        for (int j = 0; j < 2; j++) acc[i][j] = zero;

    // wave-uniform staging role: w0=A-hi, w1=A-lo, w2=W-hi, w3=W-lo
    const ushort_t* src = (w == 0) ? Ah : (w == 1) ? Al : (w == 2) ? Wh : Wl;
    ushort_t* dst = (w == 0) ? sAh : (w == 1) ? sAl : (w == 2) ? sWh : sWl;
    const size_t tbase = (size_t)((w < 2) ? bx : by) * 4 * 16;

    for (int kt = 0; kt < 16; kt++) {
        __syncthreads();
        #pragma unroll
        for (int t = 0; t < 4; t++)
            gload16(src + (tbase + (size_t)t * 16 + kt) * 512 + lo8, &dst[t * 512]);
        __syncthreads();

        bf16x8 fah[2], fal[2];
        #pragma unroll
        for (int i = 0; i < 2; i++) {
            fah[i] = *(const bf16x8*)&sAh[(wm * 2 + i) * 512 + lo8];
            fal[i] = *(const bf16x8*)&sAl[(wm * 2 + i) * 512 + lo8];
        }
        #pragma unroll
        for (int j = 0; j < 2; j++) {
            const bf16x8 fbh = *(const bf16x8*)&sWh[(wn * 2 + j) * 512 + lo8];
            const bf16x8 fbl = *(const bf16x8*)&sWl[(wn * 2 + j) * 512 + lo8];
            #pragma unroll
            for (int i = 0; i < 2; i++) {
                acc[i][j] = __builtin_amdgcn_mfma_f32_16x16x32_bf16(fah[i], fbh, acc[i][j], 0, 0, 0);
                acc[i][j] = __builtin_amdgcn_mfma_f32_16x16x32_bf16(fah[i], fbl, acc[i][j], 0, 0, 0);
                acc[i][j] = __builtin_amdgcn_mfma_f32_16x16x32_bf16(fal[i], fbh, acc[i][j], 0, 0, 0);
            }
        }
    }

    #pragma unroll
    for (int i = 0; i < 2; i++) {
        const int row0 = bx * 64 + wm * 32 + i * 16 + quad * 4;
        #pragma unroll
        for (int j = 0; j < 2; j++) {
            const int col = by * 64 + wn * 32 + j * 16 + ln;
            const float bv = bias[col];
            #pragma unroll
            for (int r = 0; r < 4; r++)
                C[(size_t)(row0 + r) * E_DIM + col] = acc[i][j][r] + bv;
        }
    }
}

extern "C" void kernel_launch(void* const* d_in, const int* in_sizes, int n_in,
                              void* d_out, int out_size, void* d_ws, size_t ws_size,
                              hipStream_t stream) {
    const float* x         = (const float*)d_in[0];
    const float* in_proj_w = (const float*)d_in[1];
    const float* in_proj_b = (const float*)d_in[2];
    const float* out_w     = (const float*)d_in[3];
    const float* out_b     = (const float*)d_in[4];
    float* out = (float*)d_out;

    const int N = B_SZ * L_SEQ;  // 8192
    const size_t NE = (size_t)N * E_DIM;  // 4.19M elems

    char* p = (char*)d_ws;
    ushort_t* xh  = (ushort_t*)p; p += NE * 2;
    ushort_t* xl  = (ushort_t*)p; p += NE * 2;
    ushort_t* w1h = (ushort_t*)p; p += (size_t)3 * E_DIM * E_DIM * 2;
    ushort_t* w1l = (ushort_t*)p; p += (size_t)3 * E_DIM * E_DIM * 2;
    ushort_t* w2h = (ushort_t*)p; p += (size_t)E_DIM * E_DIM * 2;
    ushort_t* w2l = (ushort_t*)p; p += (size_t)E_DIM * E_DIM * 2;
    ushort_t* qTh = (ushort_t*)p; p += NE * 2;
    ushort_t* qTl = (ushort_t*)p; p += NE * 2;
    ushort_t* kTh = (ushort_t*)p; p += NE * 2;
    ushort_t* kTl = (ushort_t*)p; p += NE * 2;
    ushort_t* vTh = (ushort_t*)p; p += NE * 2;
    ushort_t* ath = (ushort_t*)p; p += NE * 2;
    ushort_t* atl = (ushort_t*)p; p += NE * 2;
    // total ~79.7 MB

    convert3<<<2560, 256, 0, stream>>>(x, xh, xl, in_proj_w, w1h, w1l, out_w, w2h, w2l);

    gemm_qkv<<<dim3(64, 12), 256, 0, stream>>>(
        xh, xl, w1h, w1l, in_proj_b, qTh, qTl, kTh, kTl, vTh);

    attn_mfma<<<dim3(L_SEQ / 64, H_DIM, B_SZ), 256, 0, stream>>>(
        qTh, qTl, kTh, kTl, vTh, ath, atl);

    gemm_out<<<dim3(128, 8), 256, 0, stream>>>(
        ath, atl, w2h, w2l, out_b, out);
}